// Round 12
// baseline (2363.247 us; speedup 1.0000x reference)
//
#include <hip/hip_runtime.h>
#include <hip/hip_fp16.h>

#define T_LEN 192

typedef unsigned long long u64;
typedef _Float16 f16x8 __attribute__((ext_vector_type(8)));
typedef float f32x4 __attribute__((ext_vector_type(4)));

// ws float offsets
#define OFF_X1F   0          // X1F [192][64 tile][16 b][16 row] f32 (MFMA fragment layout)
#define OFF_XPRE  3145728    // [192][16][1024]
#define OFF_XB3   6291456    // x@Ws3 + Ws_b  [192][16][256]
#define OFF_HSB   7077888    // hsB [16][192][256]
#define OFF_P     7864320    // u64 [16][8 sp][192 tp]  (sp-major: producer-private lines)
#define OFF_H     7921664    // u64 [16][256]
#define OFF_HX    7929856    // u64 [2][16][128]  (lstm pair exchange, b-major)
#define OFF_TICKET 7938048   // u32 [9]: per-XCD cnt[8] + chosen (inside zero range)
#define OFF_HP    7946240    // u64 [16][8 sp][256 c]  (sp-major: producer-private lines)
#define EXCH_WORDS 147456    // covers P, H, HX, TICKET, HP

#define SMEM_TASK 148736

__device__ __forceinline__ unsigned packh2(float a, float b){
  union { __half2 h; unsigned u; } v;
  v.h = __halves2half2(__float2half(a), __float2half(b));
  return v.u;
}
__device__ __forceinline__ float2 unp2(unsigned u){
  union { unsigned u32; __half2 h; } v; v.u32 = u;
  return __half22float2(v.h);
}
__device__ __forceinline__ float fdot2(unsigned a, unsigned b, float c){
#if __has_builtin(__builtin_amdgcn_fdot2)
  typedef _Float16 h2t __attribute__((ext_vector_type(2)));
  union { unsigned u; h2t h; } ua, ub;
  ua.u = a; ub.u = b;
  return __builtin_amdgcn_fdot2(ua.h, ub.h, c, false);
#else
  float2 x = unp2(a), y = unp2(b);
  return c + x.x*y.x + x.y*y.y;
#endif
}
__device__ __forceinline__ float tanh_f(float x){
  float cx = fminf(fmaxf(x, -15.f), 15.f);
  float e = __expf(2.f * cx);
  return (e - 1.f) / (e + 1.f);
}
__device__ __forceinline__ float sigm(float x){
  float cx = fminf(fmaxf(x, -30.f), 30.f);
  return 1.f / (1.f + __expf(-cx));
}

// ---- exchange primitives ----
// slow/guaranteed path: agent scope (sc1, LLC coherence point)
__device__ __forceinline__ u64 gld64(const u64* p){
  return __hip_atomic_load(p, __ATOMIC_RELAXED, __HIP_MEMORY_SCOPE_AGENT);
}
__device__ __forceinline__ void gst64(u64* p, u64 v){
  __hip_atomic_store(p, v, __ATOMIC_RELAXED, __HIP_MEMORY_SCOPE_AGENT);
}
// fast path: sc0 — bypasses L0/L1, coheres at the per-XCD L2.
// Only effective when partners share an XCD; dual-publish guarantees
// correctness regardless (sc1 copy always exists at the LLC).
__device__ __forceinline__ u64 ld64_sc0(const u64* p){
  u64 v;
  asm volatile("global_load_dwordx2 %0, %1, off sc0\n\ts_waitcnt vmcnt(0)"
               : "=v"(v) : "v"(p) : "memory");
  return v;
}
__device__ __forceinline__ void st64_sc0(u64* p, u64 v){
  asm volatile("global_store_dwordx2 %0, %1, off sc0" :: "v"(p), "v"(v) : "memory");
}
// dual-publish: sc1 (guaranteed) first, then sc0 (fast, local L2)
__device__ __forceinline__ void pub64(u64* p, u64 v){
  gst64(p, v);
  st64_sc0(p, v);
}
// dual-path poll for one tagged u64
__device__ __forceinline__ u64 poll_tag(const u64* p, unsigned want){
  for (int k = 1; ; ++k) {
    u64 v = ld64_sc0(p);
    if ((unsigned)v == want) return v;
    if ((k & 7) == 0) {
      v = gld64(p);
      if ((unsigned)v == want) return v;
      __builtin_amdgcn_s_sleep(1);
    }
  }
}

__global__ __launch_bounds__(256) void initk(float* p, int n){
  int i = blockIdx.x * blockDim.x + threadIdx.x;
  int stride = gridDim.x * blockDim.x;
  for (; i < n; i += stride) p[i] = 0.f;
}

// MFMA x-projections: fused GEMM M=3072, K=256, N=2304, split-f16 hi/lo.
// 2 timesteps per block. (round-6 proven version, unchanged)
__global__ __launch_bounds__(256) void proj3m(const float* __restrict__ x,
                                              const float* __restrict__ W_ih,
                                              const float* __restrict__ b_l,
                                              const float* __restrict__ Wc,
                                              const float* __restrict__ bc,
                                              const float* __restrict__ Ws_w,
                                              const float* __restrict__ Ws_b,
                                              float* __restrict__ ws){
  __shared__ unsigned xhi[2][16 * 136];
  __shared__ unsigned xlo[2][16 * 136];
  const int bx = blockIdx.x, t0 = blockIdx.y * 2, tid = threadIdx.x;

  #pragma unroll
  for (int tt = 0; tt < 2; ++tt) {
    int row = tid >> 4, c0 = (tid & 15) * 16;
    const float* xp = &x[((t0 + tt) * 16 + row) * 256 + c0];
    #pragma unroll
    for (int i = 0; i < 8; ++i) {
      float2 v = *(const float2*)&xp[2 * i];
      _Float16 h0 = (_Float16)v.x, h1 = (_Float16)v.y;
      float l0 = v.x - (float)h0, l1 = v.y - (float)h1;
      union { _Float16 h[2]; unsigned u; } ph, pl;
      ph.h[0] = h0; ph.h[1] = h1;
      pl.h[0] = (_Float16)l0; pl.h[1] = (_Float16)l1;
      xhi[tt][row * 136 + c0 / 2 + i] = ph.u;
      xlo[tt][row * 136 + c0 / 2 + i] = pl.u;
    }
  }

  const int wave = tid >> 6, lane = tid & 63;
  const int b16 = lane & 15, quad = lane >> 4;
  const int n0 = bx * 64 + wave * 16;
  const float* wrow; const float* bias; int nb, mode;
  if (bx < 16)      { nb = n0;        wrow = &W_ih[(nb + b16) * 256];       bias = b_l;  mode = 0; }
  else if (bx < 32) { nb = n0 - 1024; wrow = &Wc[(nb + b16) * 768];         bias = bc;   mode = 1; }
  else              { nb = n0 - 2048; wrow = &Ws_w[(nb + b16) * 768 + 512]; bias = Ws_b; mode = 2; }

  f16x8 whi[8], wlo[8];
  #pragma unroll
  for (int kk = 0; kk < 8; ++kk) {
    const float* wp = wrow + kk * 32 + quad * 8;
    f16x8 h, l;
    #pragma unroll
    for (int j = 0; j < 8; ++j) {
      float v = wp[j];
      _Float16 hh = (_Float16)v;
      h[j] = hh; l[j] = (_Float16)(v - (float)hh);
    }
    whi[kk] = h; wlo[kk] = l;
  }
  f32x4 acc[2];
  #pragma unroll
  for (int tt = 0; tt < 2; ++tt)
    #pragma unroll
    for (int r = 0; r < 4; ++r) acc[tt][r] = bias[nb + quad * 4 + r];
  __syncthreads();

  #pragma unroll
  for (int kk = 0; kk < 8; ++kk) {
    #pragma unroll
    for (int tt = 0; tt < 2; ++tt) {
      union { uint4 u; f16x8 h; } bh, bl;
      bh.u = *(const uint4*)&xhi[tt][b16 * 136 + kk * 16 + quad * 4];
      bl.u = *(const uint4*)&xlo[tt][b16 * 136 + kk * 16 + quad * 4];
      acc[tt] = __builtin_amdgcn_mfma_f32_16x16x32_f16(whi[kk], bh.h, acc[tt], 0, 0, 0);
      acc[tt] = __builtin_amdgcn_mfma_f32_16x16x32_f16(wlo[kk], bh.h, acc[tt], 0, 0, 0);
      acc[tt] = __builtin_amdgcn_mfma_f32_16x16x32_f16(whi[kk], bl.h, acc[tt], 0, 0, 0);
    }
  }

  #pragma unroll
  for (int tt = 0; tt < 2; ++tt) {
    int t = t0 + tt;
    float4 res; res.x = acc[tt][0]; res.y = acc[tt][1]; res.z = acc[tt][2]; res.w = acc[tt][3];
    if (mode == 0) {
      *(float4*)&ws[OFF_X1F + (((u64)t * 64 + (n0 >> 4)) * 16 + b16) * 16 + quad * 4] = res;
    } else if (mode == 1) {
      *(float4*)&ws[OFF_XPRE + ((u64)t * 16 + b16) * 1024 + nb + quad * 4] = res;
    } else {
      *(float4*)&ws[OFF_XB3 + ((u64)t * 16 + b16) * 256 + nb + quad * 4] = res;
    }
  }
}

// Shared LSTM: 2 worker WGs x 512 thr elected onto ONE XCD (ticket, round-2
// proven machinery); W_hh resident in VGPRs, MFMA 16x16x32_f16.
// Exchange via dual-publish (sc1 + sc0): same-XCD partners see each other
// through the local L2 (fast); fallback path guarantees progress regardless.
__global__ __launch_bounds__(512) void lstm_kernel(const float* __restrict__ X1F,
                                                   const float* __restrict__ W_hh,
                                                   float* __restrict__ hsB,
                                                   u64* __restrict__ hx,
                                                   unsigned* __restrict__ ticket){
  __shared__ unsigned hT[16 * 136];   // [b][k2], row stride 136 u32
  __shared__ int role_s;
  const int tid = threadIdx.x;

  // ---- XCD co-location ticket: first XCD to register 2 blocks wins ----
  if (tid == 0) {
    int xcc = (int)__builtin_amdgcn_s_getreg(20 | (31 << 11)) & 7;
    unsigned slot = __hip_atomic_fetch_add(&ticket[xcc], 1u,
                        __ATOMIC_RELAXED, __HIP_MEMORY_SCOPE_AGENT);
    int role = -1;
    if (slot < 2u) {
      if (slot == 1u) {
        unsigned expv = 0u;
        __hip_atomic_compare_exchange_strong(&ticket[8], &expv, (unsigned)(xcc + 1),
            __ATOMIC_RELAXED, __ATOMIC_RELAXED, __HIP_MEMORY_SCOPE_AGENT);
      }
      unsigned ch;
      do {
        ch = __hip_atomic_load(&ticket[8], __ATOMIC_RELAXED, __HIP_MEMORY_SCOPE_AGENT);
      } while (ch == 0u);   // pigeonhole: 16 blocks on 8 XCDs -> some XCD gets 2
      if (ch == (unsigned)(xcc + 1)) role = (int)slot;
    }
    role_s = role;
  }
  __syncthreads();
  const int wg = role_s;
  if (wg < 0) return;                 // non-elected blocks exit

  const int wave = tid >> 6, lane = tid & 63;
  const int b16 = lane & 15, quad = lane >> 4;
  const int jb = wg * 8 + wave;
  const int peerbase = (1 - wg) * 64;   // peer jp range base

  f16x8 wf[4][8];
  #pragma unroll
  for (int g = 0; g < 4; ++g) {
    #pragma unroll
    for (int kk = 0; kk < 8; ++kk) {
      int row = g * 256 + jb * 16 + b16;
      const float* wp = &W_hh[row * 256 + kk * 32 + quad * 8];
      f16x8 v;
      #pragma unroll
      for (int j = 0; j < 8; ++j) v[j] = (_Float16)wp[j];
      wf[g][kk] = v;
    }
  }
  for (int i = tid; i < 16 * 136; i += 512) hT[i] = 0u;
  float cst[4] = {0.f, 0.f, 0.f, 0.f};
  __syncthreads();

  for (int t = 0; t < T_LEN; ++t) {
    float4 xi[4];
    #pragma unroll
    for (int g = 0; g < 4; ++g)
      xi[g] = *(const float4*)&X1F[((t * 64 + g * 16 + jb) * 16 + b16) * 16 + quad * 4];

    if (t > 0) {
      const u64* src = &hx[((u64)((t - 1) & 1)) * 2048];
      int bbq = tid >> 5, k2 = tid & 31;
      int jp0 = peerbase + 2 * k2;
      const u64* ap = &src[bbq * 128 + jp0];
      u64 v0, v1;
      for (int k = 1; ; ++k) {
        v0 = ld64_sc0(ap);
        v1 = ld64_sc0(ap + 1);
        if ((unsigned)v0 == (unsigned)t && (unsigned)v1 == (unsigned)t) break;
        if ((k & 7) == 0) {
          v0 = gld64(ap); v1 = gld64(ap + 1);
          if ((unsigned)v0 == (unsigned)t && (unsigned)v1 == (unsigned)t) break;
          __builtin_amdgcn_s_sleep(1);
        }
      }
      hT[bbq * 136 + jp0]     = (unsigned)(v0 >> 32);
      hT[bbq * 136 + jp0 + 1] = (unsigned)(v1 >> 32);
    }
    __syncthreads();

    f32x4 acc[4];
    #pragma unroll
    for (int g = 0; g < 4; ++g) {
      f32x4 a; a[0]=xi[g].x; a[1]=xi[g].y; a[2]=xi[g].z; a[3]=xi[g].w;
      acc[g] = a;
    }
    #pragma unroll
    for (int kk = 0; kk < 8; ++kk) {
      union { uint4 u; f16x8 h; } bv;
      bv.u = *(const uint4*)&hT[b16 * 136 + kk * 16 + quad * 4];
      #pragma unroll
      for (int g = 0; g < 4; ++g)
        acc[g] = __builtin_amdgcn_mfma_f32_16x16x32_f16(wf[g][kk], bv.h, acc[g], 0, 0, 0);
    }
    __syncthreads();

    float hv[4];
    #pragma unroll
    for (int r = 0; r < 4; ++r) {
      float pi = acc[0][r], pf = acc[1][r], pg = acc[2][r], po = acc[3][r];
      float cn = fmaf(sigm(pf), cst[r], sigm(pi) * tanh_f(pg));
      hv[r] = sigm(po) * tanh_f(cn);
      cst[r] = cn;
    }
    int j0 = jb * 16 + quad * 4;
    int jp = j0 >> 1;                   // even
    unsigned p01 = packh2(hv[0], hv[1]);
    unsigned p23 = packh2(hv[2], hv[3]);
    // publish FIRST: sc1 pair (guaranteed), then sc0 pair (fast L2 path)
    u64* dst = &hx[((u64)(t & 1)) * 2048];
    u64* ap = &dst[b16 * 128 + jp];
    u64 r0 = ((u64)p01 << 32) | (unsigned)(t + 1);
    u64 r1 = ((u64)p23 << 32) | (unsigned)(t + 1);
    gst64(ap, r0);
    gst64(ap + 1, r1);
    st64_sc0(ap, r0);
    st64_sc0(ap + 1, r1);
    *(float4*)&hsB[(b16 * 192 + t) * 256 + j0] = make_float4(hv[0], hv[1], hv[2], hv[3]);
    hT[b16 * 136 + jp]     = p01;
    hT[b16 * 136 + jp + 1] = p23;
  }
}

// Task loop: 128 WGs x 1024 thr; bb = bid&15, s = bid>>4 owns c in [32s,32s+32).
// Round-10 structure (2 RTT/step, sp-major mailboxes); delta: dual-path
// (sc0 fast / sc1 guaranteed) polls + dual-publish. Shard groups {bb+16k}
// are ≡ bb (mod 8) -> same XCD under round-robin dispatch -> L2-local fast path.
__global__ __launch_bounds__(1024) void task_kernel(
    const float* __restrict__ xb3, const float* __restrict__ xpre,
    const float* __restrict__ hsB, const float* __restrict__ Us_w,
    const float* __restrict__ Us_b, const float* __restrict__ Wc,
    const float* __restrict__ Ws_w,
    u64* __restrict__ Pbuf, u64* __restrict__ Hbuf, u64* __restrict__ HPbuf,
    float* __restrict__ out){
  extern __shared__ char smem[];
  // prologue views
  unsigned* hsL  = (unsigned*)smem;               // [192][129] u32
  unsigned* Ws1L = (unsigned*)(smem + 99072);     // [32][129]
  float*    baseS= (float*)(smem + 115584);       // [192][33]
  // main views
  unsigned* WcH  = (unsigned*)smem;               // 16384 u32: Wc h-part
  unsigned* Ws2P = (unsigned*)(smem + 65536);     // [256 c][17] u32: Ws2 own-K slice
  float* prel    = (float*)(smem + 82944);        // [128][13]
  float* eel     = (float*)(smem + 89600);        // 192
  unsigned* h2l  = (unsigned*)(smem + 90368);     // 128 (full h pairs)
  unsigned* h2own= (unsigned*)(smem + 90880);     // 16 (own h slice pairs)
  float* hterml  = (float*)(smem + 90944);        // 32
  float* usl     = (float*)(smem + 91072);        // 32
  float* msc     = (float*)(smem + 91200);        // 1
  unsigned* G2   = (unsigned*)(smem + 99072);     // [128][97] u32

  const int tid = threadIdx.x;
  const int bb = blockIdx.x & 15;
  const int s  = blockIdx.x >> 4;

  // ---- P1: stage hs (f16) + Ws1 slice ----
  for (int idx = tid; idx < 24576; idx += 1024) {
    int tp = idx >> 7, k2 = idx & 127;
    const float* hp = &hsB[(bb * 192 + tp) * 256 + 2 * k2];
    hsL[tp * 129 + k2] = packh2(hp[0], hp[1]);
  }
  for (int idx = tid; idx < 4096; idx += 1024) {
    int c = idx >> 7, k2 = idx & 127;
    const float* wp = &Ws_w[(32 * s + c) * 768 + 2 * k2];
    Ws1L[c * 129 + k2] = packh2(wp[0], wp[1]);
  }
  __syncthreads();
  // ---- P2: base_s = xb3 + hs @ Ws1^T ----
  {
    int c = tid & 31, g = tid >> 5;
    float a6[6];
    #pragma unroll
    for (int j = 0; j < 6; ++j)
      a6[j] = xb3[((g * 6 + j) * 16 + bb) * 256 + 32 * s + c];
    for (int k2 = 0; k2 < 128; ++k2) {
      unsigned wv = Ws1L[c * 129 + k2];
      #pragma unroll
      for (int j = 0; j < 6; ++j)
        a6[j] = fdot2(wv, hsL[(g * 6 + j) * 129 + k2], a6[j]);
    }
    #pragma unroll
    for (int j = 0; j < 6; ++j)
      baseS[(g * 6 + j) * 33 + c] = a6[j];
  }
  __syncthreads();
  // ---- P3a: persistent base registers ----
  unsigned bs4[4] = {0u, 0u, 0u, 0u};
  if (tid < 768) {
    int tp = tid >> 2, q = tid & 3;
    #pragma unroll
    for (int j2 = 0; j2 < 4; ++j2)
      bs4[j2] = packh2(baseS[tp * 33 + q * 8 + 2 * j2],
                       baseS[tp * 33 + q * 8 + 2 * j2 + 1]);
  }
  __syncthreads();
  // ---- P3b: G2[l][j] = f16 pairs over t of (Wc_R[l,:] @ hs[t,:]) ----
  {
    int l = tid & 127, tg = tid >> 7;
    int row = (l >> 5) * 256 + 32 * s + (l & 31);
    const float* wr = &Wc[row * 768 + 256];
    float acc[24];
    #pragma unroll
    for (int i = 0; i < 24; ++i) acc[i] = 0.f;
    for (int kc = 0; kc < 128; kc += 16) {
      unsigned wv[16];
      #pragma unroll
      for (int i = 0; i < 16; ++i) {
        float2 wp2 = *(const float2*)&wr[2 * (kc + i)];
        wv[i] = packh2(wp2.x, wp2.y);
      }
      #pragma unroll
      for (int tt = 0; tt < 24; ++tt) {
        const unsigned* hp = &hsL[(tg * 24 + tt) * 129 + kc];
        float a = acc[tt];
        #pragma unroll
        for (int i = 0; i < 16; ++i) a = fdot2(wv[i], hp[i], a);
        acc[tt] = a;
      }
    }
    #pragma unroll
    for (int i = 0; i < 12; ++i)
      G2[l * 97 + tg * 12 + i] = packh2(acc[2 * i], acc[2 * i + 1]);
  }
  __syncthreads();
  // ---- P4: main weight fills ----
  for (int idx = tid; idx < 16384; idx += 1024) {
    int j = idx & 3, l = (idx >> 2) & 127, k2q = idx >> 9;
    int k2 = k2q * 4 + j;
    int row = (l >> 5) * 256 + 32 * s + (l & 31);
    const float* wp = &Wc[row * 768 + 512 + 2 * k2];   // h-part cols
    WcH[idx] = packh2(wp[0], wp[1]);
  }
  for (int idx = tid; idx < 4096; idx += 1024) {
    int c = idx >> 4, j = idx & 15;                    // Ws2[:, own h K-slice]
    const float* wp = &Ws_w[c * 768 + 256 + 2 * (16 * s + j)];
    Ws2P[c * 17 + j] = packh2(wp[0], wp[1]);
  }
  if (tid < 32) usl[tid] = Us_w[32 * s + tid];
  const float usb = Us_b[0];
  __syncthreads();

  u64* Pb  = Pbuf + (bb * 8) * 192;        // [8 sp][192 tp]
  u64* Hb  = Hbuf + bb * 256;
  u64* HPb = HPbuf + (bb * 8) * 256;       // [8 sp][256 c]
  const uint4* wp4 = (const uint4*)WcH;
  const uint4* av4 = (const uint4*)h2l;
  float creg = 0.f;       // c-state (tid<32)

  for (int t = 0; t < T_LEN; ++t) {
    const unsigned seq = (unsigned)(t + 1);
    float xp0 = 0.f, xp1 = 0.f, xp2 = 0.f, xp3 = 0.f;
    if (tid < 32) {
      const float* xq = &xpre[(t * 16 + bb) * 1024 + 32 * s + tid];
      xp0 = xq[0]; xp1 = xq[256]; xp2 = xq[512]; xp3 = xq[768];
    }
    // S1: poll h (full) + hterm partials (own 32 c), one RTT (dual-path)
    if (t > 0) {
      if (tid < 256) {
        int c = tid >> 3, sp = tid & 7;
        u64 v = poll_tag(&HPb[sp * 256 + 32 * s + c], (unsigned)t);
        float a = __uint_as_float((unsigned)(v >> 32));
        a += __shfl_xor(a, 1); a += __shfl_xor(a, 2); a += __shfl_xor(a, 4);
        if (sp == 0) hterml[c] = a;
      } else if (tid < 512) {
        int col = tid - 256;
        u64 v = poll_tag(&Hb[col], (unsigned)t);
        float hvv = __uint_as_float((unsigned)(v >> 32));
        float hp_ = __shfl_xor(hvv, 1);
        if ((col & 1) == 0) h2l[col >> 1] = packh2(hvv, hp_);
      }
    } else {
      if (tid < 32) hterml[tid] = 0.f;
      if (tid < 128) h2l[tid] = 0u;
    }
    __syncthreads();                 // B1
    // S5: score partials over own 32 c for all 192 tp; publish p_s
    if (tid < 768) {
      int tp = tid >> 2, q = tid & 3;
      float p = 0.f;
      #pragma unroll
      for (int m = 0; m < 4; ++m) {
        float2 bv = unp2(bs4[m]);
        int c0 = q * 8 + 2 * m;
        p += usl[c0]     * tanh_f(bv.x + hterml[c0]);
        p += usl[c0 + 1] * tanh_f(bv.y + hterml[c0 + 1]);
      }
      p += __shfl_xor(p, 1);
      p += __shfl_xor(p, 2);
      if ((tid & 3) == 0)
        pub64(&Pb[s * 192 + tp], ((u64)__float_as_uint(p) << 32) | seq);
    }
    // hgate GEMV (p-RTT shadow): pre_h[l] partials, 8-way K-split
    {
      int l = tid & 127, kq = tid >> 7;
      float a = 0.f;
      #pragma unroll
      for (int i = 0; i < 4; ++i) {
        uint4 w4 = wp4[(kq * 4 + i) * 128 + l];
        uint4 a4 = av4[kq * 4 + i];
        a = fdot2(w4.x, a4.x, a); a = fdot2(w4.y, a4.y, a);
        a = fdot2(w4.z, a4.z, a); a = fdot2(w4.w, a4.w, a);
      }
      prel[l * 13 + kq] = a;
    }
    // S6: p poll (8 scattered u64, sc0 fast loads + guaranteed fallback)
    if (tid < 192) {
      const u64 *q0 = &Pb[0 * 192 + tid], *q1 = &Pb[1 * 192 + tid];
      const u64 *q2 = &Pb[2 * 192 + tid], *q3 = &Pb[3 * 192 + tid];
      const u64 *q4 = &Pb[4 * 192 + tid], *q5 = &Pb[5 * 192 + tid];
      const u64 *q6 = &Pb[6 * 192 + tid], *q7 = &Pb[7 * 192 + tid];
      u64 v0, v1, v2, v3, v4, v5, v6, v7;
      for (int k = 1; ; ++k) {
        asm volatile(
          "global_load_dwordx2 %0, %8, off sc0\n\t"
          "global_load_dwordx2 %1, %9, off sc0\n\t"
          "global_load_dwordx2 %2, %10, off sc0\n\t"
          "global_load_dwordx2 %3, %11, off sc0\n\t"
          "global_load_dwordx2 %4, %12, off sc0\n\t"
          "global_load_dwordx2 %5, %13, off sc0\n\t"
          "global_load_dwordx2 %6, %14, off sc0\n\t"
          "global_load_dwordx2 %7, %15, off sc0\n\t"
          "s_waitcnt vmcnt(0)"
          : "=&v"(v0), "=&v"(v1), "=&v"(v2), "=&v"(v3),
            "=&v"(v4), "=&v"(v5), "=&v"(v6), "=&v"(v7)
          : "v"(q0), "v"(q1), "v"(q2), "v"(q3),
            "v"(q4), "v"(q5), "v"(q6), "v"(q7)
          : "memory");
        bool ok = (unsigned)v0 == seq && (unsigned)v1 == seq &&
                  (unsigned)v2 == seq && (unsigned)v3 == seq &&
                  (unsigned)v4 == seq && (unsigned)v5 == seq &&
                  (unsigned)v6 == seq && (unsigned)v7 == seq;
        if (ok) break;
        if ((k & 7) == 0) {
          v0 = gld64(q0); v1 = gld64(q1); v2 = gld64(q2); v3 = gld64(q3);
          v4 = gld64(q4); v5 = gld64(q5); v6 = gld64(q6); v7 = gld64(q7);
          ok = (unsigned)v0 == seq && (unsigned)v1 == seq &&
               (unsigned)v2 == seq && (unsigned)v3 == seq &&
               (unsigned)v4 == seq && (unsigned)v5 == seq &&
               (unsigned)v6 == seq && (unsigned)v7 == seq;
          if (ok) break;
          __builtin_amdgcn_s_sleep(1);
        }
      }
      float sum = __uint_as_float((unsigned)(v0 >> 32)) +
                  __uint_as_float((unsigned)(v1 >> 32)) +
                  __uint_as_float((unsigned)(v2 >> 32)) +
                  __uint_as_float((unsigned)(v3 >> 32)) +
                  __uint_as_float((unsigned)(v4 >> 32)) +
                  __uint_as_float((unsigned)(v5 >> 32)) +
                  __uint_as_float((unsigned)(v6 >> 32)) +
                  __uint_as_float((unsigned)(v7 >> 32));
      eel[tid] = __expf(sum + usb);
    }
    __syncthreads();                 // B5
    // msc reduce (wave0) + G-part (tid>=512)
    if (tid < 64) {
      float aa = eel[tid] + eel[tid + 64] + eel[tid + 128];
      #pragma unroll
      for (int off = 32; off >= 1; off >>= 1) aa += __shfl_xor(aa, off);
      if (tid == 0) msc[0] = 1.f / aa;
    }
    if (tid >= 512) {
      int l = (tid - 512) & 127, tq = (tid - 512) >> 7;
      const unsigned* gp = &G2[l * 97 + tq * 24];
      const float2* ep = (const float2*)&eel[tq * 48];
      float a = 0.f;
      #pragma unroll
      for (int i = 0; i < 24; ++i) {
        float2 g = unp2(gp[i]);
        float2 e = ep[i];
        a = fmaf(g.x, e.x, a); a = fmaf(g.y, e.y, a);
      }
      prel[l * 13 + 8 + tq] = a;
    }
    __syncthreads();                 // B9
    // epilogue: gates for own 32 h-cols; publish h early
    if (tid < 32) {
      float m = msc[0];
      float pr[4];
      #pragma unroll
      for (int g = 0; g < 4; ++g) {
        const float* pp = &prel[(g * 32 + tid) * 13];
        float hsum = pp[0] + pp[1] + pp[2] + pp[3] + pp[4] + pp[5] + pp[6] + pp[7];
        float gsum = pp[8] + pp[9] + pp[10] + pp[11];
        pr[g] = hsum + m * gsum;
      }
      pr[0] += xp0; pr[1] += xp1; pr[2] += xp2; pr[3] += xp3;
      float cn = fmaf(sigm(pr[1]), creg, sigm(pr[0]) * tanh_f(pr[2]));
      float hh = sigm(pr[3]) * tanh_f(cn);
      creg = cn;
      pub64(&Hb[32 * s + tid], ((u64)__float_as_uint(hh) << 32) | seq);
      out[(bb * 192 + t) * 256 + 32 * s + tid] = hh;
      float hp_ = __shfl_xor(hh, 1);
      if ((tid & 1) == 0) h2own[tid >> 1] = packh2(hh, hp_);
    }
    __syncthreads();                 // B10
    // producer-side hterm partials: hpart[c] = Ws2[c, own K] @ h_own; publish
    if (tid < 256) {
      float a = 0.f;
      const unsigned* wp = &Ws2P[tid * 17];
      #pragma unroll
      for (int j = 0; j < 16; ++j) a = fdot2(wp[j], h2own[j], a);
      pub64(&HPb[s * 256 + tid], ((u64)__float_as_uint(a) << 32) | seq);
    }
  }
}

extern "C" void kernel_launch(void* const* d_in, const int* in_sizes, int n_in,
                              void* d_out, int out_size, void* d_ws, size_t ws_size,
                              hipStream_t stream) {
  (void)in_sizes; (void)n_in; (void)out_size; (void)ws_size;
  const float* x    = (const float*)d_in[0];
  const float* W_ih = (const float*)d_in[1];
  const float* W_hh = (const float*)d_in[2];
  const float* b_l  = (const float*)d_in[3];
  const float* Ws_w = (const float*)d_in[4];
  const float* Ws_b = (const float*)d_in[5];
  const float* Us_w = (const float*)d_in[6];
  const float* Us_b = (const float*)d_in[7];
  const float* Wc   = (const float*)d_in[8];
  const float* bc   = (const float*)d_in[9];
  float* out = (float*)d_out;
  float* ws = (float*)d_ws;

  (void)hipFuncSetAttribute((const void*)task_kernel,
                            hipFuncAttributeMaxDynamicSharedMemorySize, 160 * 1024);

  // zero exchange region (P, H, HX, TICKET, HP — seq tags restart each launch)
  initk<<<64, 256, 0, stream>>>(ws + OFF_P, EXCH_WORDS);

  // fused MFMA x-projections: X1F (fragment layout), xpre, xb3
  proj3m<<<dim3(36, 96), 256, 0, stream>>>(x, W_ih, b_l, Wc, bc, Ws_w, Ws_b, ws);

  // shared LSTM: 16 candidates, 2 elected same-XCD workers, W_hh in VGPRs
  lstm_kernel<<<16, 512, 0, stream>>>(ws + OFF_X1F, W_hh, ws + OFF_HSB,
                                      (u64*)(ws + OFF_HX),
                                      (unsigned*)(ws + OFF_TICKET));

  // task loop
  task_kernel<<<128, 1024, SMEM_TASK, stream>>>(
      ws + OFF_XB3, ws + OFF_XPRE, ws + OFF_HSB, Us_w, Us_b, Wc, Ws_w,
      (u64*)(ws + OFF_P), (u64*)(ws + OFF_H), (u64*)(ws + OFF_HP), out);
}

// Round 13
// 1620.839 us; speedup vs baseline: 1.4580x; 1.4580x over previous
//
#include <hip/hip_runtime.h>
#include <hip/hip_fp16.h>

#define T_LEN 192

typedef unsigned long long u64;
typedef _Float16 f16x8 __attribute__((ext_vector_type(8)));
typedef float f32x4 __attribute__((ext_vector_type(4)));

// ws float offsets
#define OFF_X1F   0          // X1F [192][64 tile][16 b][16 row] f32 (MFMA fragment layout)
#define OFF_XPRE  3145728    // [192][16][1024]
#define OFF_XB3   6291456    // x@Ws3 + Ws_b  [192][16][256]
#define OFF_HSB   7077888    // hsB [16][192][256]
#define OFF_P     7864320    // u64 [16][8 sp][192 tp]  (sp-major: producer-private lines)
#define OFF_H     7921664    // u64 [16][256]
#define OFF_HX    7929856    // u64 [2][16][128]  (lstm pair exchange, b-major)
#define OFF_HP    7946240    // u64 [16][8 sp][256 c]  (sp-major: producer-private lines)
#define EXCH_WORDS 147456    // covers P, H, HX, HP

#define SMEM_TASK 148736

__device__ __forceinline__ unsigned packh2(float a, float b){
  union { __half2 h; unsigned u; } v;
  v.h = __halves2half2(__float2half(a), __float2half(b));
  return v.u;
}
__device__ __forceinline__ float2 unp2(unsigned u){
  union { unsigned u32; __half2 h; } v; v.u32 = u;
  return __half22float2(v.h);
}
__device__ __forceinline__ float fdot2(unsigned a, unsigned b, float c){
#if __has_builtin(__builtin_amdgcn_fdot2)
  typedef _Float16 h2t __attribute__((ext_vector_type(2)));
  union { unsigned u; h2t h; } ua, ub;
  ua.u = a; ub.u = b;
  return __builtin_amdgcn_fdot2(ua.h, ub.h, c, false);
#else
  float2 x = unp2(a), y = unp2(b);
  return c + x.x*y.x + x.y*y.y;
#endif
}
__device__ __forceinline__ float tanh_f(float x){
  float cx = fminf(fmaxf(x, -15.f), 15.f);
  float e = __expf(2.f * cx);
  return (e - 1.f) / (e + 1.f);
}
__device__ __forceinline__ float sigm(float x){
  float cx = fminf(fmaxf(x, -30.f), 30.f);
  return 1.f / (1.f + __expf(-cx));
}

__device__ __forceinline__ u64 gld64(const u64* p){
  return __hip_atomic_load(p, __ATOMIC_RELAXED, __HIP_MEMORY_SCOPE_AGENT);
}
__device__ __forceinline__ void gst64(u64* p, u64 v){
  __hip_atomic_store(p, v, __ATOMIC_RELAXED, __HIP_MEMORY_SCOPE_AGENT);
}

__global__ __launch_bounds__(256) void initk(float* p, int n){
  int i = blockIdx.x * blockDim.x + threadIdx.x;
  int stride = gridDim.x * blockDim.x;
  for (; i < n; i += stride) p[i] = 0.f;
}

// MFMA x-projections: fused GEMM M=3072, K=256, N=2304, split-f16 hi/lo.
// 2 timesteps per block. (round-6 proven version, unchanged)
__global__ __launch_bounds__(256) void proj3m(const float* __restrict__ x,
                                              const float* __restrict__ W_ih,
                                              const float* __restrict__ b_l,
                                              const float* __restrict__ Wc,
                                              const float* __restrict__ bc,
                                              const float* __restrict__ Ws_w,
                                              const float* __restrict__ Ws_b,
                                              float* __restrict__ ws){
  __shared__ unsigned xhi[2][16 * 136];
  __shared__ unsigned xlo[2][16 * 136];
  const int bx = blockIdx.x, t0 = blockIdx.y * 2, tid = threadIdx.x;

  #pragma unroll
  for (int tt = 0; tt < 2; ++tt) {
    int row = tid >> 4, c0 = (tid & 15) * 16;
    const float* xp = &x[((t0 + tt) * 16 + row) * 256 + c0];
    #pragma unroll
    for (int i = 0; i < 8; ++i) {
      float2 v = *(const float2*)&xp[2 * i];
      _Float16 h0 = (_Float16)v.x, h1 = (_Float16)v.y;
      float l0 = v.x - (float)h0, l1 = v.y - (float)h1;
      union { _Float16 h[2]; unsigned u; } ph, pl;
      ph.h[0] = h0; ph.h[1] = h1;
      pl.h[0] = (_Float16)l0; pl.h[1] = (_Float16)l1;
      xhi[tt][row * 136 + c0 / 2 + i] = ph.u;
      xlo[tt][row * 136 + c0 / 2 + i] = pl.u;
    }
  }

  const int wave = tid >> 6, lane = tid & 63;
  const int b16 = lane & 15, quad = lane >> 4;
  const int n0 = bx * 64 + wave * 16;
  const float* wrow; const float* bias; int nb, mode;
  if (bx < 16)      { nb = n0;        wrow = &W_ih[(nb + b16) * 256];       bias = b_l;  mode = 0; }
  else if (bx < 32) { nb = n0 - 1024; wrow = &Wc[(nb + b16) * 768];         bias = bc;   mode = 1; }
  else              { nb = n0 - 2048; wrow = &Ws_w[(nb + b16) * 768 + 512]; bias = Ws_b; mode = 2; }

  f16x8 whi[8], wlo[8];
  #pragma unroll
  for (int kk = 0; kk < 8; ++kk) {
    const float* wp = wrow + kk * 32 + quad * 8;
    f16x8 h, l;
    #pragma unroll
    for (int j = 0; j < 8; ++j) {
      float v = wp[j];
      _Float16 hh = (_Float16)v;
      h[j] = hh; l[j] = (_Float16)(v - (float)hh);
    }
    whi[kk] = h; wlo[kk] = l;
  }
  f32x4 acc[2];
  #pragma unroll
  for (int tt = 0; tt < 2; ++tt)
    #pragma unroll
    for (int r = 0; r < 4; ++r) acc[tt][r] = bias[nb + quad * 4 + r];
  __syncthreads();

  #pragma unroll
  for (int kk = 0; kk < 8; ++kk) {
    #pragma unroll
    for (int tt = 0; tt < 2; ++tt) {
      union { uint4 u; f16x8 h; } bh, bl;
      bh.u = *(const uint4*)&xhi[tt][b16 * 136 + kk * 16 + quad * 4];
      bl.u = *(const uint4*)&xlo[tt][b16 * 136 + kk * 16 + quad * 4];
      acc[tt] = __builtin_amdgcn_mfma_f32_16x16x32_f16(whi[kk], bh.h, acc[tt], 0, 0, 0);
      acc[tt] = __builtin_amdgcn_mfma_f32_16x16x32_f16(wlo[kk], bh.h, acc[tt], 0, 0, 0);
      acc[tt] = __builtin_amdgcn_mfma_f32_16x16x32_f16(whi[kk], bl.h, acc[tt], 0, 0, 0);
    }
  }

  #pragma unroll
  for (int tt = 0; tt < 2; ++tt) {
    int t = t0 + tt;
    float4 res; res.x = acc[tt][0]; res.y = acc[tt][1]; res.z = acc[tt][2]; res.w = acc[tt][3];
    if (mode == 0) {
      *(float4*)&ws[OFF_X1F + (((u64)t * 64 + (n0 >> 4)) * 16 + b16) * 16 + quad * 4] = res;
    } else if (mode == 1) {
      *(float4*)&ws[OFF_XPRE + ((u64)t * 16 + b16) * 1024 + nb + quad * 4] = res;
    } else {
      *(float4*)&ws[OFF_XB3 + ((u64)t * 16 + b16) * 256 + nb + quad * 4] = res;
    }
  }
}

// Shared LSTM: 2 WGs x 512 thr; W_hh resident in VGPRs, MFMA 16x16x32_f16.
// Round-10 proven version: s_sleep poll backoff + publish-first epilogue.
__global__ __launch_bounds__(512) void lstm_kernel(const float* __restrict__ X1F,
                                                   const float* __restrict__ W_hh,
                                                   float* __restrict__ hsB,
                                                   u64* __restrict__ hx){
  __shared__ unsigned hT[16 * 136];   // [b][k2], row stride 136 u32
  const int tid = threadIdx.x;
  const int wg = blockIdx.x;
  const int wave = tid >> 6, lane = tid & 63;
  const int b16 = lane & 15, quad = lane >> 4;
  const int jb = wg * 8 + wave;
  const int peerbase = (1 - wg) * 64;   // peer jp range base

  f16x8 wf[4][8];
  #pragma unroll
  for (int g = 0; g < 4; ++g) {
    #pragma unroll
    for (int kk = 0; kk < 8; ++kk) {
      int row = g * 256 + jb * 16 + b16;
      const float* wp = &W_hh[row * 256 + kk * 32 + quad * 8];
      f16x8 v;
      #pragma unroll
      for (int j = 0; j < 8; ++j) v[j] = (_Float16)wp[j];
      wf[g][kk] = v;
    }
  }
  for (int i = tid; i < 16 * 136; i += 512) hT[i] = 0u;
  float cst[4] = {0.f, 0.f, 0.f, 0.f};
  __syncthreads();

  for (int t = 0; t < T_LEN; ++t) {
    float4 xi[4];
    #pragma unroll
    for (int g = 0; g < 4; ++g)
      xi[g] = *(const float4*)&X1F[((t * 64 + g * 16 + jb) * 16 + b16) * 16 + quad * 4];

    if (t > 0) {
      const u64* src = &hx[((u64)((t - 1) & 1)) * 2048];
      int bbq = tid >> 5, k2 = tid & 31;
      int jp0 = peerbase + 2 * k2;
      u64 v0 = gld64(&src[bbq * 128 + jp0]);
      u64 v1 = gld64(&src[bbq * 128 + jp0 + 1]);
      while ((unsigned)v0 != (unsigned)t || (unsigned)v1 != (unsigned)t) {
        __builtin_amdgcn_s_sleep(1);
        v0 = gld64(&src[bbq * 128 + jp0]);
        v1 = gld64(&src[bbq * 128 + jp0 + 1]);
      }
      hT[bbq * 136 + jp0]     = (unsigned)(v0 >> 32);
      hT[bbq * 136 + jp0 + 1] = (unsigned)(v1 >> 32);
    }
    __syncthreads();

    f32x4 acc[4];
    #pragma unroll
    for (int g = 0; g < 4; ++g) {
      f32x4 a; a[0]=xi[g].x; a[1]=xi[g].y; a[2]=xi[g].z; a[3]=xi[g].w;
      acc[g] = a;
    }
    #pragma unroll
    for (int kk = 0; kk < 8; ++kk) {
      union { uint4 u; f16x8 h; } bv;
      bv.u = *(const uint4*)&hT[b16 * 136 + kk * 16 + quad * 4];
      #pragma unroll
      for (int g = 0; g < 4; ++g)
        acc[g] = __builtin_amdgcn_mfma_f32_16x16x32_f16(wf[g][kk], bv.h, acc[g], 0, 0, 0);
    }
    __syncthreads();

    float hv[4];
    #pragma unroll
    for (int r = 0; r < 4; ++r) {
      float pi = acc[0][r], pf = acc[1][r], pg = acc[2][r], po = acc[3][r];
      float cn = fmaf(sigm(pf), cst[r], sigm(pi) * tanh_f(pg));
      hv[r] = sigm(po) * tanh_f(cn);
      cst[r] = cn;
    }
    int j0 = jb * 16 + quad * 4;
    int jp = j0 >> 1;                   // even
    unsigned p01 = packh2(hv[0], hv[1]);
    unsigned p23 = packh2(hv[2], hv[3]);
    // publish FIRST — peer's poll is waiting on these stores
    u64* dst = &hx[((u64)(t & 1)) * 2048];
    gst64(&dst[b16 * 128 + jp],     ((u64)p01 << 32) | (unsigned)(t + 1));
    gst64(&dst[b16 * 128 + jp + 1], ((u64)p23 << 32) | (unsigned)(t + 1));
    *(float4*)&hsB[(b16 * 192 + t) * 256 + j0] = make_float4(hv[0], hv[1], hv[2], hv[3]);
    hT[b16 * 136 + jp]     = p01;
    hT[b16 * 136 + jp + 1] = p23;
  }
}

// Task loop: 128 WGs x 1024 thr; bb = bid&15, s = bid>>4 owns c in [32s,32s+32).
// Round-10 proven version (2 RTT/step, sp-major mailboxes, s_sleep backoff).
__global__ __launch_bounds__(1024) void task_kernel(
    const float* __restrict__ xb3, const float* __restrict__ xpre,
    const float* __restrict__ hsB, const float* __restrict__ Us_w,
    const float* __restrict__ Us_b, const float* __restrict__ Wc,
    const float* __restrict__ Ws_w,
    u64* __restrict__ Pbuf, u64* __restrict__ Hbuf, u64* __restrict__ HPbuf,
    float* __restrict__ out){
  extern __shared__ char smem[];
  // prologue views
  unsigned* hsL  = (unsigned*)smem;               // [192][129] u32
  unsigned* Ws1L = (unsigned*)(smem + 99072);     // [32][129]
  float*    baseS= (float*)(smem + 115584);       // [192][33]
  // main views
  unsigned* WcH  = (unsigned*)smem;               // 16384 u32: Wc h-part
  unsigned* Ws2P = (unsigned*)(smem + 65536);     // [256 c][17] u32: Ws2 own-K slice
  float* prel    = (float*)(smem + 82944);        // [128][13]
  float* eel     = (float*)(smem + 89600);        // 192
  unsigned* h2l  = (unsigned*)(smem + 90368);     // 128 (full h pairs)
  unsigned* h2own= (unsigned*)(smem + 90880);     // 16 (own h slice pairs)
  float* hterml  = (float*)(smem + 90944);        // 32
  float* usl     = (float*)(smem + 91072);        // 32
  float* msc     = (float*)(smem + 91200);        // 1
  unsigned* G2   = (unsigned*)(smem + 99072);     // [128][97] u32

  const int tid = threadIdx.x;
  const int bb = blockIdx.x & 15;
  const int s  = blockIdx.x >> 4;

  // ---- P1: stage hs (f16) + Ws1 slice ----
  for (int idx = tid; idx < 24576; idx += 1024) {
    int tp = idx >> 7, k2 = idx & 127;
    const float* hp = &hsB[(bb * 192 + tp) * 256 + 2 * k2];
    hsL[tp * 129 + k2] = packh2(hp[0], hp[1]);
  }
  for (int idx = tid; idx < 4096; idx += 1024) {
    int c = idx >> 7, k2 = idx & 127;
    const float* wp = &Ws_w[(32 * s + c) * 768 + 2 * k2];
    Ws1L[c * 129 + k2] = packh2(wp[0], wp[1]);
  }
  __syncthreads();
  // ---- P2: base_s = xb3 + hs @ Ws1^T ----
  {
    int c = tid & 31, g = tid >> 5;
    float a6[6];
    #pragma unroll
    for (int j = 0; j < 6; ++j)
      a6[j] = xb3[((g * 6 + j) * 16 + bb) * 256 + 32 * s + c];
    for (int k2 = 0; k2 < 128; ++k2) {
      unsigned wv = Ws1L[c * 129 + k2];
      #pragma unroll
      for (int j = 0; j < 6; ++j)
        a6[j] = fdot2(wv, hsL[(g * 6 + j) * 129 + k2], a6[j]);
    }
    #pragma unroll
    for (int j = 0; j < 6; ++j)
      baseS[(g * 6 + j) * 33 + c] = a6[j];
  }
  __syncthreads();
  // ---- P3a: persistent base registers ----
  unsigned bs4[4] = {0u, 0u, 0u, 0u};
  if (tid < 768) {
    int tp = tid >> 2, q = tid & 3;
    #pragma unroll
    for (int j2 = 0; j2 < 4; ++j2)
      bs4[j2] = packh2(baseS[tp * 33 + q * 8 + 2 * j2],
                       baseS[tp * 33 + q * 8 + 2 * j2 + 1]);
  }
  __syncthreads();
  // ---- P3b: G2[l][j] = f16 pairs over t of (Wc_R[l,:] @ hs[t,:]) ----
  {
    int l = tid & 127, tg = tid >> 7;
    int row = (l >> 5) * 256 + 32 * s + (l & 31);
    const float* wr = &Wc[row * 768 + 256];
    float acc[24];
    #pragma unroll
    for (int i = 0; i < 24; ++i) acc[i] = 0.f;
    for (int kc = 0; kc < 128; kc += 16) {
      unsigned wv[16];
      #pragma unroll
      for (int i = 0; i < 16; ++i) {
        float2 wp2 = *(const float2*)&wr[2 * (kc + i)];
        wv[i] = packh2(wp2.x, wp2.y);
      }
      #pragma unroll
      for (int tt = 0; tt < 24; ++tt) {
        const unsigned* hp = &hsL[(tg * 24 + tt) * 129 + kc];
        float a = acc[tt];
        #pragma unroll
        for (int i = 0; i < 16; ++i) a = fdot2(wv[i], hp[i], a);
        acc[tt] = a;
      }
    }
    #pragma unroll
    for (int i = 0; i < 12; ++i)
      G2[l * 97 + tg * 12 + i] = packh2(acc[2 * i], acc[2 * i + 1]);
  }
  __syncthreads();
  // ---- P4: main weight fills ----
  for (int idx = tid; idx < 16384; idx += 1024) {
    int j = idx & 3, l = (idx >> 2) & 127, k2q = idx >> 9;
    int k2 = k2q * 4 + j;
    int row = (l >> 5) * 256 + 32 * s + (l & 31);
    const float* wp = &Wc[row * 768 + 512 + 2 * k2];   // h-part cols
    WcH[idx] = packh2(wp[0], wp[1]);
  }
  for (int idx = tid; idx < 4096; idx += 1024) {
    int c = idx >> 4, j = idx & 15;                    // Ws2[:, own h K-slice]
    const float* wp = &Ws_w[c * 768 + 256 + 2 * (16 * s + j)];
    Ws2P[c * 17 + j] = packh2(wp[0], wp[1]);
  }
  if (tid < 32) usl[tid] = Us_w[32 * s + tid];
  const float usb = Us_b[0];
  __syncthreads();

  u64* Pb  = Pbuf + (bb * 8) * 192;        // [8 sp][192 tp]
  u64* Hb  = Hbuf + bb * 256;
  u64* HPb = HPbuf + (bb * 8) * 256;       // [8 sp][256 c]
  const uint4* wp4 = (const uint4*)WcH;
  const uint4* av4 = (const uint4*)h2l;
  float creg = 0.f;       // c-state (tid<32)

  for (int t = 0; t < T_LEN; ++t) {
    const unsigned seq = (unsigned)(t + 1);
    float xp0 = 0.f, xp1 = 0.f, xp2 = 0.f, xp3 = 0.f;
    if (tid < 32) {
      const float* xq = &xpre[(t * 16 + bb) * 1024 + 32 * s + tid];
      xp0 = xq[0]; xp1 = xq[256]; xp2 = xq[512]; xp3 = xq[768];
    }
    // S1: poll h (full) + hterm partials (own 32 c), one RTT
    if (t > 0) {
      if (tid < 256) {
        int c = tid >> 3, sp = tid & 7;       // all 8 sp for c within one wave
        u64 v = gld64(&HPb[sp * 256 + 32 * s + c]);
        while ((unsigned)v != (unsigned)t) {
          __builtin_amdgcn_s_sleep(1);
          v = gld64(&HPb[sp * 256 + 32 * s + c]);
        }
        float a = __uint_as_float((unsigned)(v >> 32));
        a += __shfl_xor(a, 1); a += __shfl_xor(a, 2); a += __shfl_xor(a, 4);
        if (sp == 0) hterml[c] = a;
      } else if (tid < 512) {
        int col = tid - 256;
        u64 v = gld64(&Hb[col]);
        while ((unsigned)v != (unsigned)t) {
          __builtin_amdgcn_s_sleep(1);
          v = gld64(&Hb[col]);
        }
        float hvv = __uint_as_float((unsigned)(v >> 32));
        float hp_ = __shfl_xor(hvv, 1);
        if ((col & 1) == 0) h2l[col >> 1] = packh2(hvv, hp_);
      }
    } else {
      if (tid < 32) hterml[tid] = 0.f;
      if (tid < 128) h2l[tid] = 0u;
    }
    __syncthreads();                 // B1
    // S5: score partials over own 32 c for all 192 tp; publish p_s
    if (tid < 768) {
      int tp = tid >> 2, q = tid & 3;
      float p = 0.f;
      #pragma unroll
      for (int m = 0; m < 4; ++m) {
        float2 bv = unp2(bs4[m]);
        int c0 = q * 8 + 2 * m;
        p += usl[c0]     * tanh_f(bv.x + hterml[c0]);
        p += usl[c0 + 1] * tanh_f(bv.y + hterml[c0 + 1]);
      }
      p += __shfl_xor(p, 1);
      p += __shfl_xor(p, 2);
      if ((tid & 3) == 0)
        gst64(&Pb[s * 192 + tp], ((u64)__float_as_uint(p) << 32) | seq);
    }
    // hgate GEMV (p-RTT shadow): pre_h[l] partials, 8-way K-split
    {
      int l = tid & 127, kq = tid >> 7;
      float a = 0.f;
      #pragma unroll
      for (int i = 0; i < 4; ++i) {
        uint4 w4 = wp4[(kq * 4 + i) * 128 + l];
        uint4 a4 = av4[kq * 4 + i];
        a = fdot2(w4.x, a4.x, a); a = fdot2(w4.y, a4.y, a);
        a = fdot2(w4.z, a4.z, a); a = fdot2(w4.w, a4.w, a);
      }
      prel[l * 13 + kq] = a;
    }
    // S6: p poll + exp (bounded scores, no max-sub)
    if (tid < 192) {
      u64 v[8];
      for (;;) {
        bool ok = true;
        #pragma unroll
        for (int sp = 0; sp < 8; ++sp) {
          v[sp] = gld64(&Pb[sp * 192 + tid]);
          ok &= ((unsigned)v[sp] == seq);
        }
        if (ok) break;
        __builtin_amdgcn_s_sleep(1);
      }
      float sum = 0.f;
      #pragma unroll
      for (int sp = 0; sp < 8; ++sp) sum += __uint_as_float((unsigned)(v[sp] >> 32));
      eel[tid] = __expf(sum + usb);
    }
    __syncthreads();                 // B5
    // msc reduce (wave0) + G-part (tid>=512)
    if (tid < 64) {
      float aa = eel[tid] + eel[tid + 64] + eel[tid + 128];
      #pragma unroll
      for (int off = 32; off >= 1; off >>= 1) aa += __shfl_xor(aa, off);
      if (tid == 0) msc[0] = 1.f / aa;
    }
    if (tid >= 512) {
      int l = (tid - 512) & 127, tq = (tid - 512) >> 7;
      const unsigned* gp = &G2[l * 97 + tq * 24];
      const float2* ep = (const float2*)&eel[tq * 48];
      float a = 0.f;
      #pragma unroll
      for (int i = 0; i < 24; ++i) {
        float2 g = unp2(gp[i]);
        float2 e = ep[i];
        a = fmaf(g.x, e.x, a); a = fmaf(g.y, e.y, a);
      }
      prel[l * 13 + 8 + tq] = a;
    }
    __syncthreads();                 // B9
    // epilogue: gates for own 32 h-cols; publish h early
    if (tid < 32) {
      float m = msc[0];
      float pr[4];
      #pragma unroll
      for (int g = 0; g < 4; ++g) {
        const float* pp = &prel[(g * 32 + tid) * 13];
        float hsum = pp[0] + pp[1] + pp[2] + pp[3] + pp[4] + pp[5] + pp[6] + pp[7];
        float gsum = pp[8] + pp[9] + pp[10] + pp[11];
        pr[g] = hsum + m * gsum;
      }
      pr[0] += xp0; pr[1] += xp1; pr[2] += xp2; pr[3] += xp3;
      float cn = fmaf(sigm(pr[1]), creg, sigm(pr[0]) * tanh_f(pr[2]));
      float hh = sigm(pr[3]) * tanh_f(cn);
      creg = cn;
      gst64(&Hb[32 * s + tid], ((u64)__float_as_uint(hh) << 32) | seq);
      out[(bb * 192 + t) * 256 + 32 * s + tid] = hh;
      float hp_ = __shfl_xor(hh, 1);
      if ((tid & 1) == 0) h2own[tid >> 1] = packh2(hh, hp_);
    }
    __syncthreads();                 // B10
    // producer-side hterm partials: hpart[c] = Ws2[c, own K] @ h_own; publish
    if (tid < 256) {
      float a = 0.f;
      const unsigned* wp = &Ws2P[tid * 17];
      #pragma unroll
      for (int j = 0; j < 16; ++j) a = fdot2(wp[j], h2own[j], a);
      gst64(&HPb[s * 256 + tid], ((u64)__float_as_uint(a) << 32) | seq);
    }
  }
}

extern "C" void kernel_launch(void* const* d_in, const int* in_sizes, int n_in,
                              void* d_out, int out_size, void* d_ws, size_t ws_size,
                              hipStream_t stream) {
  (void)in_sizes; (void)n_in; (void)out_size; (void)ws_size;
  const float* x    = (const float*)d_in[0];
  const float* W_ih = (const float*)d_in[1];
  const float* W_hh = (const float*)d_in[2];
  const float* b_l  = (const float*)d_in[3];
  const float* Ws_w = (const float*)d_in[4];
  const float* Ws_b = (const float*)d_in[5];
  const float* Us_w = (const float*)d_in[6];
  const float* Us_b = (const float*)d_in[7];
  const float* Wc   = (const float*)d_in[8];
  const float* bc   = (const float*)d_in[9];
  float* out = (float*)d_out;
  float* ws = (float*)d_ws;

  (void)hipFuncSetAttribute((const void*)task_kernel,
                            hipFuncAttributeMaxDynamicSharedMemorySize, 160 * 1024);

  // zero exchange region (P, H, HX, HP — seq tags restart at 1 each launch)
  initk<<<64, 256, 0, stream>>>(ws + OFF_P, EXCH_WORDS);

  // fused MFMA x-projections: X1F (fragment layout), xpre, xb3
  proj3m<<<dim3(36, 96), 256, 0, stream>>>(x, W_ih, b_l, Wc, bc, Ws_w, Ws_b, ws);

  // shared LSTM: 2 persistent WGs, W_hh in VGPRs via MFMA
  lstm_kernel<<<2, 512, 0, stream>>>(ws + OFF_X1F, W_hh, ws + OFF_HSB,
                                     (u64*)(ws + OFF_HX));

  // task loop
  task_kernel<<<128, 1024, SMEM_TASK, stream>>>(
      ws + OFF_XB3, ws + OFF_XPRE, ws + OFF_HSB, Us_w, Us_b, Wc, Ws_w,
      (u64*)(ws + OFF_P), (u64*)(ws + OFF_H), (u64*)(ws + OFF_HP), out);
}

// Round 14
// 1513.964 us; speedup vs baseline: 1.5610x; 1.0706x over previous
//
#include <hip/hip_runtime.h>
#include <hip/hip_fp16.h>

#define T_LEN 192

typedef unsigned long long u64;
typedef _Float16 f16x8 __attribute__((ext_vector_type(8)));
typedef float f32x4 __attribute__((ext_vector_type(4)));

// ws float offsets
#define OFF_X1F   0          // x1 [192][16][1024] f32 (plain layout)
#define OFF_XPRE  3145728    // [192][16][1024]
#define OFF_XB3   6291456    // x@Ws3 + Ws_b  [192][16][256]
#define OFF_HSB   7077888    // hsB [16][192][256]
#define OFF_P     7864320    // u64 [16][8 sp][192 tp]  (sp-major: producer-private lines)
#define OFF_H     7921664    // u64 [16][256]
#define OFF_HP    7946240    // u64 [16][8 sp][256 c]  (sp-major: producer-private lines)
#define EXCH_WORDS 147456    // covers P, H, (old HX), HP

#define SMEM_TASK 148736
// lstm_b2 dynamic smem: wl4 131072 + hT4 512 + pre 4096
#define SMEM_LSTM 135680

__device__ __forceinline__ unsigned packh2(float a, float b){
  union { __half2 h; unsigned u; } v;
  v.h = __halves2half2(__float2half(a), __float2half(b));
  return v.u;
}
__device__ __forceinline__ float2 unp2(unsigned u){
  union { unsigned u32; __half2 h; } v; v.u32 = u;
  return __half22float2(v.h);
}
__device__ __forceinline__ float fdot2(unsigned a, unsigned b, float c){
#if __has_builtin(__builtin_amdgcn_fdot2)
  typedef _Float16 h2t __attribute__((ext_vector_type(2)));
  union { unsigned u; h2t h; } ua, ub;
  ua.u = a; ub.u = b;
  return __builtin_amdgcn_fdot2(ua.h, ub.h, c, false);
#else
  float2 x = unp2(a), y = unp2(b);
  return c + x.x*y.x + x.y*y.y;
#endif
}
__device__ __forceinline__ float tanh_f(float x){
  float cx = fminf(fmaxf(x, -15.f), 15.f);
  float e = __expf(2.f * cx);
  return (e - 1.f) / (e + 1.f);
}
__device__ __forceinline__ float sigm(float x){
  float cx = fminf(fmaxf(x, -30.f), 30.f);
  return 1.f / (1.f + __expf(-cx));
}

__device__ __forceinline__ u64 gld64(const u64* p){
  return __hip_atomic_load(p, __ATOMIC_RELAXED, __HIP_MEMORY_SCOPE_AGENT);
}
__device__ __forceinline__ void gst64(u64* p, u64 v){
  __hip_atomic_store(p, v, __ATOMIC_RELAXED, __HIP_MEMORY_SCOPE_AGENT);
}

__global__ __launch_bounds__(256) void initk(float* p, int n){
  int i = blockIdx.x * blockDim.x + threadIdx.x;
  int stride = gridDim.x * blockDim.x;
  for (; i < n; i += stride) p[i] = 0.f;
}

// MFMA x-projections: fused GEMM M=3072, K=256, N=2304, split-f16 hi/lo.
// 2 timesteps per block. Mode-0 (x1) output in PLAIN [t][b][1024] layout
// (round-7 verified variant) for the batch-parallel LSTM.
__global__ __launch_bounds__(256) void proj3m(const float* __restrict__ x,
                                              const float* __restrict__ W_ih,
                                              const float* __restrict__ b_l,
                                              const float* __restrict__ Wc,
                                              const float* __restrict__ bc,
                                              const float* __restrict__ Ws_w,
                                              const float* __restrict__ Ws_b,
                                              float* __restrict__ ws){
  __shared__ unsigned xhi[2][16 * 136];
  __shared__ unsigned xlo[2][16 * 136];
  const int bx = blockIdx.x, t0 = blockIdx.y * 2, tid = threadIdx.x;

  #pragma unroll
  for (int tt = 0; tt < 2; ++tt) {
    int row = tid >> 4, c0 = (tid & 15) * 16;
    const float* xp = &x[((t0 + tt) * 16 + row) * 256 + c0];
    #pragma unroll
    for (int i = 0; i < 8; ++i) {
      float2 v = *(const float2*)&xp[2 * i];
      _Float16 h0 = (_Float16)v.x, h1 = (_Float16)v.y;
      float l0 = v.x - (float)h0, l1 = v.y - (float)h1;
      union { _Float16 h[2]; unsigned u; } ph, pl;
      ph.h[0] = h0; ph.h[1] = h1;
      pl.h[0] = (_Float16)l0; pl.h[1] = (_Float16)l1;
      xhi[tt][row * 136 + c0 / 2 + i] = ph.u;
      xlo[tt][row * 136 + c0 / 2 + i] = pl.u;
    }
  }

  const int wave = tid >> 6, lane = tid & 63;
  const int b16 = lane & 15, quad = lane >> 4;
  const int n0 = bx * 64 + wave * 16;
  const float* wrow; const float* bias; int nb, mode;
  if (bx < 16)      { nb = n0;        wrow = &W_ih[(nb + b16) * 256];       bias = b_l;  mode = 0; }
  else if (bx < 32) { nb = n0 - 1024; wrow = &Wc[(nb + b16) * 768];         bias = bc;   mode = 1; }
  else              { nb = n0 - 2048; wrow = &Ws_w[(nb + b16) * 768 + 512]; bias = Ws_b; mode = 2; }

  f16x8 whi[8], wlo[8];
  #pragma unroll
  for (int kk = 0; kk < 8; ++kk) {
    const float* wp = wrow + kk * 32 + quad * 8;
    f16x8 h, l;
    #pragma unroll
    for (int j = 0; j < 8; ++j) {
      float v = wp[j];
      _Float16 hh = (_Float16)v;
      h[j] = hh; l[j] = (_Float16)(v - (float)hh);
    }
    whi[kk] = h; wlo[kk] = l;
  }
  f32x4 acc[2];
  #pragma unroll
  for (int tt = 0; tt < 2; ++tt)
    #pragma unroll
    for (int r = 0; r < 4; ++r) acc[tt][r] = bias[nb + quad * 4 + r];
  __syncthreads();

  #pragma unroll
  for (int kk = 0; kk < 8; ++kk) {
    #pragma unroll
    for (int tt = 0; tt < 2; ++tt) {
      union { uint4 u; f16x8 h; } bh, bl;
      bh.u = *(const uint4*)&xhi[tt][b16 * 136 + kk * 16 + quad * 4];
      bl.u = *(const uint4*)&xlo[tt][b16 * 136 + kk * 16 + quad * 4];
      acc[tt] = __builtin_amdgcn_mfma_f32_16x16x32_f16(whi[kk], bh.h, acc[tt], 0, 0, 0);
      acc[tt] = __builtin_amdgcn_mfma_f32_16x16x32_f16(wlo[kk], bh.h, acc[tt], 0, 0, 0);
      acc[tt] = __builtin_amdgcn_mfma_f32_16x16x32_f16(whi[kk], bl.h, acc[tt], 0, 0, 0);
    }
  }

  #pragma unroll
  for (int tt = 0; tt < 2; ++tt) {
    int t = t0 + tt;
    float4 res; res.x = acc[tt][0]; res.y = acc[tt][1]; res.z = acc[tt][2]; res.w = acc[tt][3];
    if (mode == 0) {
      *(float4*)&ws[OFF_X1F + ((u64)t * 16 + b16) * 1024 + nb + quad * 4] = res;
    } else if (mode == 1) {
      *(float4*)&ws[OFF_XPRE + ((u64)t * 16 + b16) * 1024 + nb + quad * 4] = res;
    } else {
      *(float4*)&ws[OFF_XB3 + ((u64)t * 16 + b16) * 256 + nb + quad * 4] = res;
    }
  }
}

// Shared LSTM, batch-parallel, ZERO exchange: 16 WGs x 1024 thr, one per batch.
// W_hh f16: K=0..191 in 96 VGPRs/thread, K=192..255 in 128 KB LDS (lane-contiguous
// b128 reads). h(t-1) in LDS (broadcast uint4 reads). Thread tid owns gate-row tid.
// 2 barriers/step; round-7 verified structure with the L2-stream flaw removed.
__global__ __launch_bounds__(1024, 4) void lstm_b2(const float* __restrict__ x1,
                                                   const float* __restrict__ W_hh,
                                                   float* __restrict__ hsB){
  extern __shared__ char smem[];
  uint4* wl4 = (uint4*)smem;                    // [8][1024] uint4 (K=192..255)
  uint4* hT4 = (uint4*)(smem + 131072);         // [32] uint4: h as f16 pairs
  float* pre = (float*)(smem + 131584);         // [1024]

  const int tid = threadIdx.x;
  const int bb = blockIdx.x;
  const float* wrow = &W_hh[tid * 256];

  // ---- one-time: W row -> 96 VGPRs (K=0..191) + LDS (K=192..255) ----
  unsigned wr[96];
  #pragma unroll
  for (int m = 0; m < 96; ++m)
    wr[m] = packh2(wrow[2 * m], wrow[2 * m + 1]);
  #pragma unroll
  for (int i = 0; i < 8; ++i) {
    const float* wp = &wrow[192 + 8 * i];
    uint4 v;
    v.x = packh2(wp[0], wp[1]); v.y = packh2(wp[2], wp[3]);
    v.z = packh2(wp[4], wp[5]); v.w = packh2(wp[6], wp[7]);
    wl4[i * 1024 + tid] = v;
  }
  if (tid < 32) hT4[tid] = make_uint4(0u, 0u, 0u, 0u);
  float cst = 0.f;                 // c-state (tid<256)
  __syncthreads();

  for (int t = 0; t < T_LEN; ++t) {
    float a = x1[(t * 16 + bb) * 1024 + tid];
    // VGPR W part: K=0..191
    #pragma unroll
    for (int i = 0; i < 24; ++i) {
      uint4 hv = hT4[i];
      a = fdot2(wr[4 * i],     hv.x, a);
      a = fdot2(wr[4 * i + 1], hv.y, a);
      a = fdot2(wr[4 * i + 2], hv.z, a);
      a = fdot2(wr[4 * i + 3], hv.w, a);
    }
    // LDS W part: K=192..255
    #pragma unroll
    for (int i = 0; i < 8; ++i) {
      uint4 wv = wl4[i * 1024 + tid];
      uint4 hv = hT4[24 + i];
      a = fdot2(wv.x, hv.x, a); a = fdot2(wv.y, hv.y, a);
      a = fdot2(wv.z, hv.z, a); a = fdot2(wv.w, hv.w, a);
    }
    pre[tid] = a;
    __syncthreads();
    if (tid < 256) {
      float pi = pre[tid], pf = pre[tid + 256], pg = pre[tid + 512], po = pre[tid + 768];
      float cn = fmaf(sigm(pf), cst, sigm(pi) * tanh_f(pg));
      float hh = sigm(po) * tanh_f(cn);
      cst = cn;
      hsB[(bb * 192 + t) * 256 + tid] = hh;
      float hp_ = __shfl_xor(hh, 1);
      if ((tid & 1) == 0) ((unsigned*)hT4)[tid >> 1] = packh2(hh, hp_);
    }
    __syncthreads();
  }
}

// Task loop: 128 WGs x 1024 thr; bb = bid&15, s = bid>>4 owns c in [32s,32s+32).
// Round-10 proven version (2 RTT/step, sp-major mailboxes, s_sleep backoff).
__global__ __launch_bounds__(1024) void task_kernel(
    const float* __restrict__ xb3, const float* __restrict__ xpre,
    const float* __restrict__ hsB, const float* __restrict__ Us_w,
    const float* __restrict__ Us_b, const float* __restrict__ Wc,
    const float* __restrict__ Ws_w,
    u64* __restrict__ Pbuf, u64* __restrict__ Hbuf, u64* __restrict__ HPbuf,
    float* __restrict__ out){
  extern __shared__ char smem[];
  // prologue views
  unsigned* hsL  = (unsigned*)smem;               // [192][129] u32
  unsigned* Ws1L = (unsigned*)(smem + 99072);     // [32][129]
  float*    baseS= (float*)(smem + 115584);       // [192][33]
  // main views
  unsigned* WcH  = (unsigned*)smem;               // 16384 u32: Wc h-part
  unsigned* Ws2P = (unsigned*)(smem + 65536);     // [256 c][17] u32: Ws2 own-K slice
  float* prel    = (float*)(smem + 82944);        // [128][13]
  float* eel     = (float*)(smem + 89600);        // 192
  unsigned* h2l  = (unsigned*)(smem + 90368);     // 128 (full h pairs)
  unsigned* h2own= (unsigned*)(smem + 90880);     // 16 (own h slice pairs)
  float* hterml  = (float*)(smem + 90944);        // 32
  float* usl     = (float*)(smem + 91072);        // 32
  float* msc     = (float*)(smem + 91200);        // 1
  unsigned* G2   = (unsigned*)(smem + 99072);     // [128][97] u32

  const int tid = threadIdx.x;
  const int bb = blockIdx.x & 15;
  const int s  = blockIdx.x >> 4;

  // ---- P1: stage hs (f16) + Ws1 slice ----
  for (int idx = tid; idx < 24576; idx += 1024) {
    int tp = idx >> 7, k2 = idx & 127;
    const float* hp = &hsB[(bb * 192 + tp) * 256 + 2 * k2];
    hsL[tp * 129 + k2] = packh2(hp[0], hp[1]);
  }
  for (int idx = tid; idx < 4096; idx += 1024) {
    int c = idx >> 7, k2 = idx & 127;
    const float* wp = &Ws_w[(32 * s + c) * 768 + 2 * k2];
    Ws1L[c * 129 + k2] = packh2(wp[0], wp[1]);
  }
  __syncthreads();
  // ---- P2: base_s = xb3 + hs @ Ws1^T ----
  {
    int c = tid & 31, g = tid >> 5;
    float a6[6];
    #pragma unroll
    for (int j = 0; j < 6; ++j)
      a6[j] = xb3[((g * 6 + j) * 16 + bb) * 256 + 32 * s + c];
    for (int k2 = 0; k2 < 128; ++k2) {
      unsigned wv = Ws1L[c * 129 + k2];
      #pragma unroll
      for (int j = 0; j < 6; ++j)
        a6[j] = fdot2(wv, hsL[(g * 6 + j) * 129 + k2], a6[j]);
    }
    #pragma unroll
    for (int j = 0; j < 6; ++j)
      baseS[(g * 6 + j) * 33 + c] = a6[j];
  }
  __syncthreads();
  // ---- P3a: persistent base registers ----
  unsigned bs4[4] = {0u, 0u, 0u, 0u};
  if (tid < 768) {
    int tp = tid >> 2, q = tid & 3;
    #pragma unroll
    for (int j2 = 0; j2 < 4; ++j2)
      bs4[j2] = packh2(baseS[tp * 33 + q * 8 + 2 * j2],
                       baseS[tp * 33 + q * 8 + 2 * j2 + 1]);
  }
  __syncthreads();
  // ---- P3b: G2[l][j] = f16 pairs over t of (Wc_R[l,:] @ hs[t,:]) ----
  {
    int l = tid & 127, tg = tid >> 7;
    int row = (l >> 5) * 256 + 32 * s + (l & 31);
    const float* wr = &Wc[row * 768 + 256];
    float acc[24];
    #pragma unroll
    for (int i = 0; i < 24; ++i) acc[i] = 0.f;
    for (int kc = 0; kc < 128; kc += 16) {
      unsigned wv[16];
      #pragma unroll
      for (int i = 0; i < 16; ++i) {
        float2 wp2 = *(const float2*)&wr[2 * (kc + i)];
        wv[i] = packh2(wp2.x, wp2.y);
      }
      #pragma unroll
      for (int tt = 0; tt < 24; ++tt) {
        const unsigned* hp = &hsL[(tg * 24 + tt) * 129 + kc];
        float a = acc[tt];
        #pragma unroll
        for (int i = 0; i < 16; ++i) a = fdot2(wv[i], hp[i], a);
        acc[tt] = a;
      }
    }
    #pragma unroll
    for (int i = 0; i < 12; ++i)
      G2[l * 97 + tg * 12 + i] = packh2(acc[2 * i], acc[2 * i + 1]);
  }
  __syncthreads();
  // ---- P4: main weight fills ----
  for (int idx = tid; idx < 16384; idx += 1024) {
    int j = idx & 3, l = (idx >> 2) & 127, k2q = idx >> 9;
    int k2 = k2q * 4 + j;
    int row = (l >> 5) * 256 + 32 * s + (l & 31);
    const float* wp = &Wc[row * 768 + 512 + 2 * k2];   // h-part cols
    WcH[idx] = packh2(wp[0], wp[1]);
  }
  for (int idx = tid; idx < 4096; idx += 1024) {
    int c = idx >> 4, j = idx & 15;                    // Ws2[:, own h K-slice]
    const float* wp = &Ws_w[c * 768 + 256 + 2 * (16 * s + j)];
    Ws2P[c * 17 + j] = packh2(wp[0], wp[1]);
  }
  if (tid < 32) usl[tid] = Us_w[32 * s + tid];
  const float usb = Us_b[0];
  __syncthreads();

  u64* Pb  = Pbuf + (bb * 8) * 192;        // [8 sp][192 tp]
  u64* Hb  = Hbuf + bb * 256;
  u64* HPb = HPbuf + (bb * 8) * 256;       // [8 sp][256 c]
  const uint4* wp4 = (const uint4*)WcH;
  const uint4* av4 = (const uint4*)h2l;
  float creg = 0.f;       // c-state (tid<32)

  for (int t = 0; t < T_LEN; ++t) {
    const unsigned seq = (unsigned)(t + 1);
    float xp0 = 0.f, xp1 = 0.f, xp2 = 0.f, xp3 = 0.f;
    if (tid < 32) {
      const float* xq = &xpre[(t * 16 + bb) * 1024 + 32 * s + tid];
      xp0 = xq[0]; xp1 = xq[256]; xp2 = xq[512]; xp3 = xq[768];
    }
    // S1: poll h (full) + hterm partials (own 32 c), one RTT
    if (t > 0) {
      if (tid < 256) {
        int c = tid >> 3, sp = tid & 7;       // all 8 sp for c within one wave
        u64 v = gld64(&HPb[sp * 256 + 32 * s + c]);
        while ((unsigned)v != (unsigned)t) {
          __builtin_amdgcn_s_sleep(1);
          v = gld64(&HPb[sp * 256 + 32 * s + c]);
        }
        float a = __uint_as_float((unsigned)(v >> 32));
        a += __shfl_xor(a, 1); a += __shfl_xor(a, 2); a += __shfl_xor(a, 4);
        if (sp == 0) hterml[c] = a;
      } else if (tid < 512) {
        int col = tid - 256;
        u64 v = gld64(&Hb[col]);
        while ((unsigned)v != (unsigned)t) {
          __builtin_amdgcn_s_sleep(1);
          v = gld64(&Hb[col]);
        }
        float hvv = __uint_as_float((unsigned)(v >> 32));
        float hp_ = __shfl_xor(hvv, 1);
        if ((col & 1) == 0) h2l[col >> 1] = packh2(hvv, hp_);
      }
    } else {
      if (tid < 32) hterml[tid] = 0.f;
      if (tid < 128) h2l[tid] = 0u;
    }
    __syncthreads();                 // B1
    // S5: score partials over own 32 c for all 192 tp; publish p_s
    if (tid < 768) {
      int tp = tid >> 2, q = tid & 3;
      float p = 0.f;
      #pragma unroll
      for (int m = 0; m < 4; ++m) {
        float2 bv = unp2(bs4[m]);
        int c0 = q * 8 + 2 * m;
        p += usl[c0]     * tanh_f(bv.x + hterml[c0]);
        p += usl[c0 + 1] * tanh_f(bv.y + hterml[c0 + 1]);
      }
      p += __shfl_xor(p, 1);
      p += __shfl_xor(p, 2);
      if ((tid & 3) == 0)
        gst64(&Pb[s * 192 + tp], ((u64)__float_as_uint(p) << 32) | seq);
    }
    // hgate GEMV (p-RTT shadow): pre_h[l] partials, 8-way K-split
    {
      int l = tid & 127, kq = tid >> 7;
      float a = 0.f;
      #pragma unroll
      for (int i = 0; i < 4; ++i) {
        uint4 w4 = wp4[(kq * 4 + i) * 128 + l];
        uint4 a4 = av4[kq * 4 + i];
        a = fdot2(w4.x, a4.x, a); a = fdot2(w4.y, a4.y, a);
        a = fdot2(w4.z, a4.z, a); a = fdot2(w4.w, a4.w, a);
      }
      prel[l * 13 + kq] = a;
    }
    // S6: p poll + exp (bounded scores, no max-sub)
    if (tid < 192) {
      u64 v[8];
      for (;;) {
        bool ok = true;
        #pragma unroll
        for (int sp = 0; sp < 8; ++sp) {
          v[sp] = gld64(&Pb[sp * 192 + tid]);
          ok &= ((unsigned)v[sp] == seq);
        }
        if (ok) break;
        __builtin_amdgcn_s_sleep(1);
      }
      float sum = 0.f;
      #pragma unroll
      for (int sp = 0; sp < 8; ++sp) sum += __uint_as_float((unsigned)(v[sp] >> 32));
      eel[tid] = __expf(sum + usb);
    }
    __syncthreads();                 // B5
    // msc reduce (wave0) + G-part (tid>=512)
    if (tid < 64) {
      float aa = eel[tid] + eel[tid + 64] + eel[tid + 128];
      #pragma unroll
      for (int off = 32; off >= 1; off >>= 1) aa += __shfl_xor(aa, off);
      if (tid == 0) msc[0] = 1.f / aa;
    }
    if (tid >= 512) {
      int l = (tid - 512) & 127, tq = (tid - 512) >> 7;
      const unsigned* gp = &G2[l * 97 + tq * 24];
      const float2* ep = (const float2*)&eel[tq * 48];
      float a = 0.f;
      #pragma unroll
      for (int i = 0; i < 24; ++i) {
        float2 g = unp2(gp[i]);
        float2 e = ep[i];
        a = fmaf(g.x, e.x, a); a = fmaf(g.y, e.y, a);
      }
      prel[l * 13 + 8 + tq] = a;
    }
    __syncthreads();                 // B9
    // epilogue: gates for own 32 h-cols; publish h early
    if (tid < 32) {
      float m = msc[0];
      float pr[4];
      #pragma unroll
      for (int g = 0; g < 4; ++g) {
        const float* pp = &prel[(g * 32 + tid) * 13];
        float hsum = pp[0] + pp[1] + pp[2] + pp[3] + pp[4] + pp[5] + pp[6] + pp[7];
        float gsum = pp[8] + pp[9] + pp[10] + pp[11];
        pr[g] = hsum + m * gsum;
      }
      pr[0] += xp0; pr[1] += xp1; pr[2] += xp2; pr[3] += xp3;
      float cn = fmaf(sigm(pr[1]), creg, sigm(pr[0]) * tanh_f(pr[2]));
      float hh = sigm(pr[3]) * tanh_f(cn);
      creg = cn;
      gst64(&Hb[32 * s + tid], ((u64)__float_as_uint(hh) << 32) | seq);
      out[(bb * 192 + t) * 256 + 32 * s + tid] = hh;
      float hp_ = __shfl_xor(hh, 1);
      if ((tid & 1) == 0) h2own[tid >> 1] = packh2(hh, hp_);
    }
    __syncthreads();                 // B10
    // producer-side hterm partials: hpart[c] = Ws2[c, own K] @ h_own; publish
    if (tid < 256) {
      float a = 0.f;
      const unsigned* wp = &Ws2P[tid * 17];
      #pragma unroll
      for (int j = 0; j < 16; ++j) a = fdot2(wp[j], h2own[j], a);
      gst64(&HPb[s * 256 + tid], ((u64)__float_as_uint(a) << 32) | seq);
    }
  }
}

extern "C" void kernel_launch(void* const* d_in, const int* in_sizes, int n_in,
                              void* d_out, int out_size, void* d_ws, size_t ws_size,
                              hipStream_t stream) {
  (void)in_sizes; (void)n_in; (void)out_size; (void)ws_size;
  const float* x    = (const float*)d_in[0];
  const float* W_ih = (const float*)d_in[1];
  const float* W_hh = (const float*)d_in[2];
  const float* b_l  = (const float*)d_in[3];
  const float* Ws_w = (const float*)d_in[4];
  const float* Ws_b = (const float*)d_in[5];
  const float* Us_w = (const float*)d_in[6];
  const float* Us_b = (const float*)d_in[7];
  const float* Wc   = (const float*)d_in[8];
  const float* bc   = (const float*)d_in[9];
  float* out = (float*)d_out;
  float* ws = (float*)d_ws;

  (void)hipFuncSetAttribute((const void*)task_kernel,
                            hipFuncAttributeMaxDynamicSharedMemorySize, 160 * 1024);
  (void)hipFuncSetAttribute((const void*)lstm_b2,
                            hipFuncAttributeMaxDynamicSharedMemorySize, 160 * 1024);

  // zero exchange region (P, H, HP — seq tags restart at 1 each launch)
  initk<<<64, 256, 0, stream>>>(ws + OFF_P, EXCH_WORDS);

  // fused MFMA x-projections: x1 (plain), xpre, xb3
  proj3m<<<dim3(36, 96), 256, 0, stream>>>(x, W_ih, b_l, Wc, bc, Ws_w, Ws_b, ws);

  // shared LSTM: batch-parallel, zero-exchange, W_hh in VGPR(96)+LDS(128KB)
  lstm_b2<<<16, 1024, SMEM_LSTM, stream>>>(ws + OFF_X1F, W_hh, ws + OFF_HSB);

  // task loop
  task_kernel<<<128, 1024, SMEM_TASK, stream>>>(
      ws + OFF_XB3, ws + OFF_XPRE, ws + OFF_HSB, Us_w, Us_b, Wc, Ws_w,
      (u64*)(ws + OFF_P), (u64*)(ws + OFF_H), (u64*)(ws + OFF_HP), out);
}

// Round 15
// 1477.096 us; speedup vs baseline: 1.5999x; 1.0250x over previous
//
#include <hip/hip_runtime.h>
#include <hip/hip_fp16.h>

#define T_LEN 192

typedef unsigned long long u64;
typedef _Float16 f16x8 __attribute__((ext_vector_type(8)));
typedef float f32x4 __attribute__((ext_vector_type(4)));

// ws float offsets
#define OFF_X1F   0          // x1 [192][16][1024] f32 (plain layout)
#define OFF_XPRE  3145728    // [192][16][1024]
#define OFF_XB3   6291456    // x@Ws3 + Ws_b  [192][16][256]
#define OFF_HSB   7077888    // hsB [16][192][256]
#define OFF_P     7864320    // u64 [16][8 sp][192 tp]  (sp-major: producer-private lines)
#define OFF_H     7921664    // u64 [16][256]
#define OFF_HP    7946240    // u64 [16][8 sp][256 c]  (sp-major: producer-private lines)
#define EXCH_WORDS 147456    // covers P, H, HP

#define SMEM_TASK 148736
// lstm_b2 dynamic smem: wl4 131072 + hT4 512 + pre 4096
#define SMEM_LSTM 135680

__device__ __forceinline__ unsigned packh2(float a, float b){
  union { __half2 h; unsigned u; } v;
  v.h = __halves2half2(__float2half(a), __float2half(b));
  return v.u;
}
__device__ __forceinline__ float2 unp2(unsigned u){
  union { unsigned u32; __half2 h; } v; v.u32 = u;
  return __half22float2(v.h);
}
__device__ __forceinline__ float fdot2(unsigned a, unsigned b, float c){
#if __has_builtin(__builtin_amdgcn_fdot2)
  typedef _Float16 h2t __attribute__((ext_vector_type(2)));
  union { unsigned u; h2t h; } ua, ub;
  ua.u = a; ub.u = b;
  return __builtin_amdgcn_fdot2(ua.h, ub.h, c, false);
#else
  float2 x = unp2(a), y = unp2(b);
  return c + x.x*y.x + x.y*y.y;
#endif
}
__device__ __forceinline__ float tanh_f(float x){
  float cx = fminf(fmaxf(x, -15.f), 15.f);
  float e = __expf(2.f * cx);
  return (e - 1.f) / (e + 1.f);
}
__device__ __forceinline__ float sigm(float x){
  float cx = fminf(fmaxf(x, -30.f), 30.f);
  return 1.f / (1.f + __expf(-cx));
}

__device__ __forceinline__ u64 gld64(const u64* p){
  return __hip_atomic_load(p, __ATOMIC_RELAXED, __HIP_MEMORY_SCOPE_AGENT);
}
__device__ __forceinline__ void gst64(u64* p, u64 v){
  __hip_atomic_store(p, v, __ATOMIC_RELAXED, __HIP_MEMORY_SCOPE_AGENT);
}

__global__ __launch_bounds__(256) void initk(float* p, int n){
  int i = blockIdx.x * blockDim.x + threadIdx.x;
  int stride = gridDim.x * blockDim.x;
  for (; i < n; i += stride) p[i] = 0.f;
}

// MFMA x-projections: fused GEMM M=3072, K=256, N=2304, split-f16 hi/lo.
// 2 timesteps per block. Mode-0 (x1) output in PLAIN [t][b][1024] layout.
__global__ __launch_bounds__(256) void proj3m(const float* __restrict__ x,
                                              const float* __restrict__ W_ih,
                                              const float* __restrict__ b_l,
                                              const float* __restrict__ Wc,
                                              const float* __restrict__ bc,
                                              const float* __restrict__ Ws_w,
                                              const float* __restrict__ Ws_b,
                                              float* __restrict__ ws){
  __shared__ unsigned xhi[2][16 * 136];
  __shared__ unsigned xlo[2][16 * 136];
  const int bx = blockIdx.x, t0 = blockIdx.y * 2, tid = threadIdx.x;

  #pragma unroll
  for (int tt = 0; tt < 2; ++tt) {
    int row = tid >> 4, c0 = (tid & 15) * 16;
    const float* xp = &x[((t0 + tt) * 16 + row) * 256 + c0];
    #pragma unroll
    for (int i = 0; i < 8; ++i) {
      float2 v = *(const float2*)&xp[2 * i];
      _Float16 h0 = (_Float16)v.x, h1 = (_Float16)v.y;
      float l0 = v.x - (float)h0, l1 = v.y - (float)h1;
      union { _Float16 h[2]; unsigned u; } ph, pl;
      ph.h[0] = h0; ph.h[1] = h1;
      pl.h[0] = (_Float16)l0; pl.h[1] = (_Float16)l1;
      xhi[tt][row * 136 + c0 / 2 + i] = ph.u;
      xlo[tt][row * 136 + c0 / 2 + i] = pl.u;
    }
  }

  const int wave = tid >> 6, lane = tid & 63;
  const int b16 = lane & 15, quad = lane >> 4;
  const int n0 = bx * 64 + wave * 16;
  const float* wrow; const float* bias; int nb, mode;
  if (bx < 16)      { nb = n0;        wrow = &W_ih[(nb + b16) * 256];       bias = b_l;  mode = 0; }
  else if (bx < 32) { nb = n0 - 1024; wrow = &Wc[(nb + b16) * 768];         bias = bc;   mode = 1; }
  else              { nb = n0 - 2048; wrow = &Ws_w[(nb + b16) * 768 + 512]; bias = Ws_b; mode = 2; }

  f16x8 whi[8], wlo[8];
  #pragma unroll
  for (int kk = 0; kk < 8; ++kk) {
    const float* wp = wrow + kk * 32 + quad * 8;
    f16x8 h, l;
    #pragma unroll
    for (int j = 0; j < 8; ++j) {
      float v = wp[j];
      _Float16 hh = (_Float16)v;
      h[j] = hh; l[j] = (_Float16)(v - (float)hh);
    }
    whi[kk] = h; wlo[kk] = l;
  }
  f32x4 acc[2];
  #pragma unroll
  for (int tt = 0; tt < 2; ++tt)
    #pragma unroll
    for (int r = 0; r < 4; ++r) acc[tt][r] = bias[nb + quad * 4 + r];
  __syncthreads();

  #pragma unroll
  for (int kk = 0; kk < 8; ++kk) {
    #pragma unroll
    for (int tt = 0; tt < 2; ++tt) {
      union { uint4 u; f16x8 h; } bh, bl;
      bh.u = *(const uint4*)&xhi[tt][b16 * 136 + kk * 16 + quad * 4];
      bl.u = *(const uint4*)&xlo[tt][b16 * 136 + kk * 16 + quad * 4];
      acc[tt] = __builtin_amdgcn_mfma_f32_16x16x32_f16(whi[kk], bh.h, acc[tt], 0, 0, 0);
      acc[tt] = __builtin_amdgcn_mfma_f32_16x16x32_f16(wlo[kk], bh.h, acc[tt], 0, 0, 0);
      acc[tt] = __builtin_amdgcn_mfma_f32_16x16x32_f16(whi[kk], bl.h, acc[tt], 0, 0, 0);
    }
  }

  #pragma unroll
  for (int tt = 0; tt < 2; ++tt) {
    int t = t0 + tt;
    float4 res; res.x = acc[tt][0]; res.y = acc[tt][1]; res.z = acc[tt][2]; res.w = acc[tt][3];
    if (mode == 0) {
      *(float4*)&ws[OFF_X1F + ((u64)t * 16 + b16) * 1024 + nb + quad * 4] = res;
    } else if (mode == 1) {
      *(float4*)&ws[OFF_XPRE + ((u64)t * 16 + b16) * 1024 + nb + quad * 4] = res;
    } else {
      *(float4*)&ws[OFF_XB3 + ((u64)t * 16 + b16) * 256 + nb + quad * 4] = res;
    }
  }
}

// Shared LSTM, batch-parallel, ZERO exchange: 16 WGs x 1024 thr, one per batch.
// W_hh f16: K=0..191 in 96 VGPRs/thread, K=192..255 in 128 KB LDS.
// Round-15 deltas: (a) x added in epilogue sum (x1 latency hidden under fdot2s),
// (b) next-step x1 prefetch, (c) 4 independent accumulator chains.
__global__ __launch_bounds__(1024, 4) void lstm_b2(const float* __restrict__ x1,
                                                   const float* __restrict__ W_hh,
                                                   float* __restrict__ hsB){
  extern __shared__ char smem[];
  uint4* wl4 = (uint4*)smem;                    // [8][1024] uint4 (K=192..255)
  uint4* hT4 = (uint4*)(smem + 131072);         // [32] uint4: h as f16 pairs
  float* pre = (float*)(smem + 131584);         // [1024]

  const int tid = threadIdx.x;
  const int bb = blockIdx.x;
  const float* wrow = &W_hh[tid * 256];

  // ---- one-time: W row -> 96 VGPRs (K=0..191) + LDS (K=192..255) ----
  unsigned wr[96];
  #pragma unroll
  for (int m = 0; m < 96; ++m)
    wr[m] = packh2(wrow[2 * m], wrow[2 * m + 1]);
  #pragma unroll
  for (int i = 0; i < 8; ++i) {
    const float* wp = &wrow[192 + 8 * i];
    uint4 v;
    v.x = packh2(wp[0], wp[1]); v.y = packh2(wp[2], wp[3]);
    v.z = packh2(wp[4], wp[5]); v.w = packh2(wp[6], wp[7]);
    wl4[i * 1024 + tid] = v;
  }
  if (tid < 32) hT4[tid] = make_uint4(0u, 0u, 0u, 0u);
  float cst = 0.f;                 // c-state (tid<256)
  float xcur = x1[(0 * 16 + bb) * 1024 + tid];
  __syncthreads();

  for (int t = 0; t < T_LEN; ++t) {
    // prefetch next step's x1 (independent of everything this step)
    float xnext = (t + 1 < T_LEN) ? x1[((t + 1) * 16 + bb) * 1024 + tid] : 0.f;
    // 4 independent accumulator chains; x added at the end (latency hidden)
    float a0 = 0.f, a1 = 0.f, a2 = 0.f, a3 = 0.f;
    // VGPR W part: K=0..191 (24 uint4 groups, round-robin over chains)
    #pragma unroll
    for (int i = 0; i < 24; i += 4) {
      uint4 h0 = hT4[i], h1 = hT4[i + 1], h2 = hT4[i + 2], h3 = hT4[i + 3];
      a0 = fdot2(wr[4 * i],      h0.x, a0); a0 = fdot2(wr[4 * i + 1],  h0.y, a0);
      a0 = fdot2(wr[4 * i + 2],  h0.z, a0); a0 = fdot2(wr[4 * i + 3],  h0.w, a0);
      a1 = fdot2(wr[4 * i + 4],  h1.x, a1); a1 = fdot2(wr[4 * i + 5],  h1.y, a1);
      a1 = fdot2(wr[4 * i + 6],  h1.z, a1); a1 = fdot2(wr[4 * i + 7],  h1.w, a1);
      a2 = fdot2(wr[4 * i + 8],  h2.x, a2); a2 = fdot2(wr[4 * i + 9],  h2.y, a2);
      a2 = fdot2(wr[4 * i + 10], h2.z, a2); a2 = fdot2(wr[4 * i + 11], h2.w, a2);
      a3 = fdot2(wr[4 * i + 12], h3.x, a3); a3 = fdot2(wr[4 * i + 13], h3.y, a3);
      a3 = fdot2(wr[4 * i + 14], h3.z, a3); a3 = fdot2(wr[4 * i + 15], h3.w, a3);
    }
    // LDS W part: K=192..255 (8 uint4 groups, 2 per chain)
    #pragma unroll
    for (int i = 0; i < 8; i += 4) {
      uint4 w0 = wl4[(i)     * 1024 + tid];
      uint4 w1 = wl4[(i + 1) * 1024 + tid];
      uint4 w2 = wl4[(i + 2) * 1024 + tid];
      uint4 w3 = wl4[(i + 3) * 1024 + tid];
      uint4 h0 = hT4[24 + i], h1 = hT4[25 + i], h2 = hT4[26 + i], h3 = hT4[27 + i];
      a0 = fdot2(w0.x, h0.x, a0); a0 = fdot2(w0.y, h0.y, a0);
      a0 = fdot2(w0.z, h0.z, a0); a0 = fdot2(w0.w, h0.w, a0);
      a1 = fdot2(w1.x, h1.x, a1); a1 = fdot2(w1.y, h1.y, a1);
      a1 = fdot2(w1.z, h1.z, a1); a1 = fdot2(w1.w, h1.w, a1);
      a2 = fdot2(w2.x, h2.x, a2); a2 = fdot2(w2.y, h2.y, a2);
      a2 = fdot2(w2.z, h2.z, a2); a2 = fdot2(w2.w, h2.w, a2);
      a3 = fdot2(w3.x, h3.x, a3); a3 = fdot2(w3.y, h3.y, a3);
      a3 = fdot2(w3.z, h3.z, a3); a3 = fdot2(w3.w, h3.w, a3);
    }
    pre[tid] = ((a0 + a1) + (a2 + a3)) + xcur;
    __syncthreads();
    if (tid < 256) {
      float pi = pre[tid], pf = pre[tid + 256], pg = pre[tid + 512], po = pre[tid + 768];
      float cn = fmaf(sigm(pf), cst, sigm(pi) * tanh_f(pg));
      float hh = sigm(po) * tanh_f(cn);
      cst = cn;
      hsB[(bb * 192 + t) * 256 + tid] = hh;
      float hp_ = __shfl_xor(hh, 1);
      if ((tid & 1) == 0) ((unsigned*)hT4)[tid >> 1] = packh2(hh, hp_);
    }
    __syncthreads();
    xcur = xnext;
  }
}

// Task loop: 128 WGs x 1024 thr; bb = bid&15, s = bid>>4 owns c in [32s,32s+32).
// Round-10 proven version (2 RTT/step, sp-major mailboxes, s_sleep backoff).
__global__ __launch_bounds__(1024) void task_kernel(
    const float* __restrict__ xb3, const float* __restrict__ xpre,
    const float* __restrict__ hsB, const float* __restrict__ Us_w,
    const float* __restrict__ Us_b, const float* __restrict__ Wc,
    const float* __restrict__ Ws_w,
    u64* __restrict__ Pbuf, u64* __restrict__ Hbuf, u64* __restrict__ HPbuf,
    float* __restrict__ out){
  extern __shared__ char smem[];
  // prologue views
  unsigned* hsL  = (unsigned*)smem;               // [192][129] u32
  unsigned* Ws1L = (unsigned*)(smem + 99072);     // [32][129]
  float*    baseS= (float*)(smem + 115584);       // [192][33]
  // main views
  unsigned* WcH  = (unsigned*)smem;               // 16384 u32: Wc h-part
  unsigned* Ws2P = (unsigned*)(smem + 65536);     // [256 c][17] u32: Ws2 own-K slice
  float* prel    = (float*)(smem + 82944);        // [128][13]
  float* eel     = (float*)(smem + 89600);        // 192
  unsigned* h2l  = (unsigned*)(smem + 90368);     // 128 (full h pairs)
  unsigned* h2own= (unsigned*)(smem + 90880);     // 16 (own h slice pairs)
  float* hterml  = (float*)(smem + 90944);        // 32
  float* usl     = (float*)(smem + 91072);        // 32
  float* msc     = (float*)(smem + 91200);        // 1
  unsigned* G2   = (unsigned*)(smem + 99072);     // [128][97] u32

  const int tid = threadIdx.x;
  const int bb = blockIdx.x & 15;
  const int s  = blockIdx.x >> 4;

  // ---- P1: stage hs (f16) + Ws1 slice ----
  for (int idx = tid; idx < 24576; idx += 1024) {
    int tp = idx >> 7, k2 = idx & 127;
    const float* hp = &hsB[(bb * 192 + tp) * 256 + 2 * k2];
    hsL[tp * 129 + k2] = packh2(hp[0], hp[1]);
  }
  for (int idx = tid; idx < 4096; idx += 1024) {
    int c = idx >> 7, k2 = idx & 127;
    const float* wp = &Ws_w[(32 * s + c) * 768 + 2 * k2];
    Ws1L[c * 129 + k2] = packh2(wp[0], wp[1]);
  }
  __syncthreads();
  // ---- P2: base_s = xb3 + hs @ Ws1^T ----
  {
    int c = tid & 31, g = tid >> 5;
    float a6[6];
    #pragma unroll
    for (int j = 0; j < 6; ++j)
      a6[j] = xb3[((g * 6 + j) * 16 + bb) * 256 + 32 * s + c];
    for (int k2 = 0; k2 < 128; ++k2) {
      unsigned wv = Ws1L[c * 129 + k2];
      #pragma unroll
      for (int j = 0; j < 6; ++j)
        a6[j] = fdot2(wv, hsL[(g * 6 + j) * 129 + k2], a6[j]);
    }
    #pragma unroll
    for (int j = 0; j < 6; ++j)
      baseS[(g * 6 + j) * 33 + c] = a6[j];
  }
  __syncthreads();
  // ---- P3a: persistent base registers ----
  unsigned bs4[4] = {0u, 0u, 0u, 0u};
  if (tid < 768) {
    int tp = tid >> 2, q = tid & 3;
    #pragma unroll
    for (int j2 = 0; j2 < 4; ++j2)
      bs4[j2] = packh2(baseS[tp * 33 + q * 8 + 2 * j2],
                       baseS[tp * 33 + q * 8 + 2 * j2 + 1]);
  }
  __syncthreads();
  // ---- P3b: G2[l][j] = f16 pairs over t of (Wc_R[l,:] @ hs[t,:]) ----
  {
    int l = tid & 127, tg = tid >> 7;
    int row = (l >> 5) * 256 + 32 * s + (l & 31);
    const float* wr = &Wc[row * 768 + 256];
    float acc[24];
    #pragma unroll
    for (int i = 0; i < 24; ++i) acc[i] = 0.f;
    for (int kc = 0; kc < 128; kc += 16) {
      unsigned wv[16];
      #pragma unroll
      for (int i = 0; i < 16; ++i) {
        float2 wp2 = *(const float2*)&wr[2 * (kc + i)];
        wv[i] = packh2(wp2.x, wp2.y);
      }
      #pragma unroll
      for (int tt = 0; tt < 24; ++tt) {
        const unsigned* hp = &hsL[(tg * 24 + tt) * 129 + kc];
        float a = acc[tt];
        #pragma unroll
        for (int i = 0; i < 16; ++i) a = fdot2(wv[i], hp[i], a);
        acc[tt] = a;
      }
    }
    #pragma unroll
    for (int i = 0; i < 12; ++i)
      G2[l * 97 + tg * 12 + i] = packh2(acc[2 * i], acc[2 * i + 1]);
  }
  __syncthreads();
  // ---- P4: main weight fills ----
  for (int idx = tid; idx < 16384; idx += 1024) {
    int j = idx & 3, l = (idx >> 2) & 127, k2q = idx >> 9;
    int k2 = k2q * 4 + j;
    int row = (l >> 5) * 256 + 32 * s + (l & 31);
    const float* wp = &Wc[row * 768 + 512 + 2 * k2];   // h-part cols
    WcH[idx] = packh2(wp[0], wp[1]);
  }
  for (int idx = tid; idx < 4096; idx += 1024) {
    int c = idx >> 4, j = idx & 15;                    // Ws2[:, own h K-slice]
    const float* wp = &Ws_w[c * 768 + 256 + 2 * (16 * s + j)];
    Ws2P[c * 17 + j] = packh2(wp[0], wp[1]);
  }
  if (tid < 32) usl[tid] = Us_w[32 * s + tid];
  const float usb = Us_b[0];
  __syncthreads();

  u64* Pb  = Pbuf + (bb * 8) * 192;        // [8 sp][192 tp]
  u64* Hb  = Hbuf + bb * 256;
  u64* HPb = HPbuf + (bb * 8) * 256;       // [8 sp][256 c]
  const uint4* wp4 = (const uint4*)WcH;
  const uint4* av4 = (const uint4*)h2l;
  float creg = 0.f;       // c-state (tid<32)

  for (int t = 0; t < T_LEN; ++t) {
    const unsigned seq = (unsigned)(t + 1);
    float xp0 = 0.f, xp1 = 0.f, xp2 = 0.f, xp3 = 0.f;
    if (tid < 32) {
      const float* xq = &xpre[(t * 16 + bb) * 1024 + 32 * s + tid];
      xp0 = xq[0]; xp1 = xq[256]; xp2 = xq[512]; xp3 = xq[768];
    }
    // S1: poll h (full) + hterm partials (own 32 c), one RTT
    if (t > 0) {
      if (tid < 256) {
        int c = tid >> 3, sp = tid & 7;       // all 8 sp for c within one wave
        u64 v = gld64(&HPb[sp * 256 + 32 * s + c]);
        while ((unsigned)v != (unsigned)t) {
          __builtin_amdgcn_s_sleep(1);
          v = gld64(&HPb[sp * 256 + 32 * s + c]);
        }
        float a = __uint_as_float((unsigned)(v >> 32));
        a += __shfl_xor(a, 1); a += __shfl_xor(a, 2); a += __shfl_xor(a, 4);
        if (sp == 0) hterml[c] = a;
      } else if (tid < 512) {
        int col = tid - 256;
        u64 v = gld64(&Hb[col]);
        while ((unsigned)v != (unsigned)t) {
          __builtin_amdgcn_s_sleep(1);
          v = gld64(&Hb[col]);
        }
        float hvv = __uint_as_float((unsigned)(v >> 32));
        float hp_ = __shfl_xor(hvv, 1);
        if ((col & 1) == 0) h2l[col >> 1] = packh2(hvv, hp_);
      }
    } else {
      if (tid < 32) hterml[tid] = 0.f;
      if (tid < 128) h2l[tid] = 0u;
    }
    __syncthreads();                 // B1
    // S5: score partials over own 32 c for all 192 tp; publish p_s
    if (tid < 768) {
      int tp = tid >> 2, q = tid & 3;
      float p = 0.f;
      #pragma unroll
      for (int m = 0; m < 4; ++m) {
        float2 bv = unp2(bs4[m]);
        int c0 = q * 8 + 2 * m;
        p += usl[c0]     * tanh_f(bv.x + hterml[c0]);
        p += usl[c0 + 1] * tanh_f(bv.y + hterml[c0 + 1]);
      }
      p += __shfl_xor(p, 1);
      p += __shfl_xor(p, 2);
      if ((tid & 3) == 0)
        gst64(&Pb[s * 192 + tp], ((u64)__float_as_uint(p) << 32) | seq);
    }
    // hgate GEMV (p-RTT shadow): pre_h[l] partials, 8-way K-split
    {
      int l = tid & 127, kq = tid >> 7;
      float a = 0.f;
      #pragma unroll
      for (int i = 0; i < 4; ++i) {
        uint4 w4 = wp4[(kq * 4 + i) * 128 + l];
        uint4 a4 = av4[kq * 4 + i];
        a = fdot2(w4.x, a4.x, a); a = fdot2(w4.y, a4.y, a);
        a = fdot2(w4.z, a4.z, a); a = fdot2(w4.w, a4.w, a);
      }
      prel[l * 13 + kq] = a;
    }
    // S6: p poll + exp (bounded scores, no max-sub)
    if (tid < 192) {
      u64 v[8];
      for (;;) {
        bool ok = true;
        #pragma unroll
        for (int sp = 0; sp < 8; ++sp) {
          v[sp] = gld64(&Pb[sp * 192 + tid]);
          ok &= ((unsigned)v[sp] == seq);
        }
        if (ok) break;
        __builtin_amdgcn_s_sleep(1);
      }
      float sum = 0.f;
      #pragma unroll
      for (int sp = 0; sp < 8; ++sp) sum += __uint_as_float((unsigned)(v[sp] >> 32));
      eel[tid] = __expf(sum + usb);
    }
    __syncthreads();                 // B5
    // msc reduce (wave0) + G-part (tid>=512)
    if (tid < 64) {
      float aa = eel[tid] + eel[tid + 64] + eel[tid + 128];
      #pragma unroll
      for (int off = 32; off >= 1; off >>= 1) aa += __shfl_xor(aa, off);
      if (tid == 0) msc[0] = 1.f / aa;
    }
    if (tid >= 512) {
      int l = (tid - 512) & 127, tq = (tid - 512) >> 7;
      const unsigned* gp = &G2[l * 97 + tq * 24];
      const float2* ep = (const float2*)&eel[tq * 48];
      float a = 0.f;
      #pragma unroll
      for (int i = 0; i < 24; ++i) {
        float2 g = unp2(gp[i]);
        float2 e = ep[i];
        a = fmaf(g.x, e.x, a); a = fmaf(g.y, e.y, a);
      }
      prel[l * 13 + 8 + tq] = a;
    }
    __syncthreads();                 // B9
    // epilogue: gates for own 32 h-cols; publish h early
    if (tid < 32) {
      float m = msc[0];
      float pr[4];
      #pragma unroll
      for (int g = 0; g < 4; ++g) {
        const float* pp = &prel[(g * 32 + tid) * 13];
        float hsum = pp[0] + pp[1] + pp[2] + pp[3] + pp[4] + pp[5] + pp[6] + pp[7];
        float gsum = pp[8] + pp[9] + pp[10] + pp[11];
        pr[g] = hsum + m * gsum;
      }
      pr[0] += xp0; pr[1] += xp1; pr[2] += xp2; pr[3] += xp3;
      float cn = fmaf(sigm(pr[1]), creg, sigm(pr[0]) * tanh_f(pr[2]));
      float hh = sigm(pr[3]) * tanh_f(cn);
      creg = cn;
      gst64(&Hb[32 * s + tid], ((u64)__float_as_uint(hh) << 32) | seq);
      out[(bb * 192 + t) * 256 + 32 * s + tid] = hh;
      float hp_ = __shfl_xor(hh, 1);
      if ((tid & 1) == 0) h2own[tid >> 1] = packh2(hh, hp_);
    }
    __syncthreads();                 // B10
    // producer-side hterm partials: hpart[c] = Ws2[c, own K] @ h_own; publish
    if (tid < 256) {
      float a = 0.f;
      const unsigned* wp = &Ws2P[tid * 17];
      #pragma unroll
      for (int j = 0; j < 16; ++j) a = fdot2(wp[j], h2own[j], a);
      gst64(&HPb[s * 256 + tid], ((u64)__float_as_uint(a) << 32) | seq);
    }
  }
}

extern "C" void kernel_launch(void* const* d_in, const int* in_sizes, int n_in,
                              void* d_out, int out_size, void* d_ws, size_t ws_size,
                              hipStream_t stream) {
  (void)in_sizes; (void)n_in; (void)out_size; (void)ws_size;
  const float* x    = (const float*)d_in[0];
  const float* W_ih = (const float*)d_in[1];
  const float* W_hh = (const float*)d_in[2];
  const float* b_l  = (const float*)d_in[3];
  const float* Ws_w = (const float*)d_in[4];
  const float* Ws_b = (const float*)d_in[5];
  const float* Us_w = (const float*)d_in[6];
  const float* Us_b = (const float*)d_in[7];
  const float* Wc   = (const float*)d_in[8];
  const float* bc   = (const float*)d_in[9];
  float* out = (float*)d_out;
  float* ws = (float*)d_ws;

  (void)hipFuncSetAttribute((const void*)task_kernel,
                            hipFuncAttributeMaxDynamicSharedMemorySize, 160 * 1024);
  (void)hipFuncSetAttribute((const void*)lstm_b2,
                            hipFuncAttributeMaxDynamicSharedMemorySize, 160 * 1024);

  // zero exchange region (P, H, HP — seq tags restart at 1 each launch)
  initk<<<64, 256, 0, stream>>>(ws + OFF_P, EXCH_WORDS);

  // fused MFMA x-projections: x1 (plain), xpre, xb3
  proj3m<<<dim3(36, 96), 256, 0, stream>>>(x, W_ih, b_l, Wc, bc, Ws_w, Ws_b, ws);

  // shared LSTM: batch-parallel, zero-exchange, W_hh in VGPR(96)+LDS(128KB)
  lstm_b2<<<16, 1024, SMEM_LSTM, stream>>>(ws + OFF_X1F, W_hh, ws + OFF_HSB);

  // task loop
  task_kernel<<<128, 1024, SMEM_TASK, stream>>>(
      ws + OFF_XB3, ws + OFF_XPRE, ws + OFF_HSB, Us_w, Us_b, Wc, Ws_w,
      (u64*)(ws + OFF_P), (u64*)(ws + OFF_H), (u64*)(ws + OFF_HP), out);
}

// Round 16
// 1461.059 us; speedup vs baseline: 1.6175x; 1.0110x over previous
//
#include <hip/hip_runtime.h>
#include <hip/hip_fp16.h>

#define T_LEN 192

typedef unsigned long long u64;
typedef _Float16 f16x8 __attribute__((ext_vector_type(8)));
typedef float f32x4 __attribute__((ext_vector_type(4)));

// ws float offsets
#define OFF_X1F   0          // x1 [192][16][1024] f32 (plain layout)
#define OFF_XPRE  3145728    // [192][16][1024]
#define OFF_XB3   6291456    // x@Ws3 + Ws_b  [192][16][256]
#define OFF_HSB   7077888    // hsB [16][192][256]
#define OFF_P     7864320    // u64 [16][8 sp][192 tp]  (sp-major: producer-private lines)
#define OFF_H     7921664    // u64 [16][256]
#define OFF_HP    7946240    // u64 [16][8 sp][256 c]  (sp-major: producer-private lines)
#define EXCH_WORDS 147456    // covers P, H, HP

#define SMEM_TASK 148736
// lstm_b2 dynamic smem: wl4 131072 + hT4 512 + pre 4096
#define SMEM_LSTM 135680

__device__ __forceinline__ unsigned packh2(float a, float b){
  union { __half2 h; unsigned u; } v;
  v.h = __halves2half2(__float2half(a), __float2half(b));
  return v.u;
}
__device__ __forceinline__ float2 unp2(unsigned u){
  union { unsigned u32; __half2 h; } v; v.u32 = u;
  return __half22float2(v.h);
}
__device__ __forceinline__ float fdot2(unsigned a, unsigned b, float c){
#if __has_builtin(__builtin_amdgcn_fdot2)
  typedef _Float16 h2t __attribute__((ext_vector_type(2)));
  union { unsigned u; h2t h; } ua, ub;
  ua.u = a; ub.u = b;
  return __builtin_amdgcn_fdot2(ua.h, ub.h, c, false);
#else
  float2 x = unp2(a), y = unp2(b);
  return c + x.x*y.x + x.y*y.y;
#endif
}
__device__ __forceinline__ float tanh_f(float x){
  float cx = fminf(fmaxf(x, -15.f), 15.f);
  float e = __expf(2.f * cx);
  return (e - 1.f) / (e + 1.f);
}
__device__ __forceinline__ float sigm(float x){
  float cx = fminf(fmaxf(x, -30.f), 30.f);
  return 1.f / (1.f + __expf(-cx));
}

__device__ __forceinline__ u64 gld64(const u64* p){
  return __hip_atomic_load(p, __ATOMIC_RELAXED, __HIP_MEMORY_SCOPE_AGENT);
}
__device__ __forceinline__ void gst64(u64* p, u64 v){
  __hip_atomic_store(p, v, __ATOMIC_RELAXED, __HIP_MEMORY_SCOPE_AGENT);
}

__global__ __launch_bounds__(256) void initk(float* p, int n){
  int i = blockIdx.x * blockDim.x + threadIdx.x;
  int stride = gridDim.x * blockDim.x;
  for (; i < n; i += stride) p[i] = 0.f;
}

// MFMA x-projections: fused GEMM M=3072, K=256, N=2304, split-f16 hi/lo.
// 2 timesteps per block. Mode-0 (x1) output in PLAIN [t][b][1024] layout.
__global__ __launch_bounds__(256) void proj3m(const float* __restrict__ x,
                                              const float* __restrict__ W_ih,
                                              const float* __restrict__ b_l,
                                              const float* __restrict__ Wc,
                                              const float* __restrict__ bc,
                                              const float* __restrict__ Ws_w,
                                              const float* __restrict__ Ws_b,
                                              float* __restrict__ ws){
  __shared__ unsigned xhi[2][16 * 136];
  __shared__ unsigned xlo[2][16 * 136];
  const int bx = blockIdx.x, t0 = blockIdx.y * 2, tid = threadIdx.x;

  #pragma unroll
  for (int tt = 0; tt < 2; ++tt) {
    int row = tid >> 4, c0 = (tid & 15) * 16;
    const float* xp = &x[((t0 + tt) * 16 + row) * 256 + c0];
    #pragma unroll
    for (int i = 0; i < 8; ++i) {
      float2 v = *(const float2*)&xp[2 * i];
      _Float16 h0 = (_Float16)v.x, h1 = (_Float16)v.y;
      float l0 = v.x - (float)h0, l1 = v.y - (float)h1;
      union { _Float16 h[2]; unsigned u; } ph, pl;
      ph.h[0] = h0; ph.h[1] = h1;
      pl.h[0] = (_Float16)l0; pl.h[1] = (_Float16)l1;
      xhi[tt][row * 136 + c0 / 2 + i] = ph.u;
      xlo[tt][row * 136 + c0 / 2 + i] = pl.u;
    }
  }

  const int wave = tid >> 6, lane = tid & 63;
  const int b16 = lane & 15, quad = lane >> 4;
  const int n0 = bx * 64 + wave * 16;
  const float* wrow; const float* bias; int nb, mode;
  if (bx < 16)      { nb = n0;        wrow = &W_ih[(nb + b16) * 256];       bias = b_l;  mode = 0; }
  else if (bx < 32) { nb = n0 - 1024; wrow = &Wc[(nb + b16) * 768];         bias = bc;   mode = 1; }
  else              { nb = n0 - 2048; wrow = &Ws_w[(nb + b16) * 768 + 512]; bias = Ws_b; mode = 2; }

  f16x8 whi[8], wlo[8];
  #pragma unroll
  for (int kk = 0; kk < 8; ++kk) {
    const float* wp = wrow + kk * 32 + quad * 8;
    f16x8 h, l;
    #pragma unroll
    for (int j = 0; j < 8; ++j) {
      float v = wp[j];
      _Float16 hh = (_Float16)v;
      h[j] = hh; l[j] = (_Float16)(v - (float)hh);
    }
    whi[kk] = h; wlo[kk] = l;
  }
  f32x4 acc[2];
  #pragma unroll
  for (int tt = 0; tt < 2; ++tt)
    #pragma unroll
    for (int r = 0; r < 4; ++r) acc[tt][r] = bias[nb + quad * 4 + r];
  __syncthreads();

  #pragma unroll
  for (int kk = 0; kk < 8; ++kk) {
    #pragma unroll
    for (int tt = 0; tt < 2; ++tt) {
      union { uint4 u; f16x8 h; } bh, bl;
      bh.u = *(const uint4*)&xhi[tt][b16 * 136 + kk * 16 + quad * 4];
      bl.u = *(const uint4*)&xlo[tt][b16 * 136 + kk * 16 + quad * 4];
      acc[tt] = __builtin_amdgcn_mfma_f32_16x16x32_f16(whi[kk], bh.h, acc[tt], 0, 0, 0);
      acc[tt] = __builtin_amdgcn_mfma_f32_16x16x32_f16(wlo[kk], bh.h, acc[tt], 0, 0, 0);
      acc[tt] = __builtin_amdgcn_mfma_f32_16x16x32_f16(whi[kk], bl.h, acc[tt], 0, 0, 0);
    }
  }

  #pragma unroll
  for (int tt = 0; tt < 2; ++tt) {
    int t = t0 + tt;
    float4 res; res.x = acc[tt][0]; res.y = acc[tt][1]; res.z = acc[tt][2]; res.w = acc[tt][3];
    if (mode == 0) {
      *(float4*)&ws[OFF_X1F + ((u64)t * 16 + b16) * 1024 + nb + quad * 4] = res;
    } else if (mode == 1) {
      *(float4*)&ws[OFF_XPRE + ((u64)t * 16 + b16) * 1024 + nb + quad * 4] = res;
    } else {
      *(float4*)&ws[OFF_XB3 + ((u64)t * 16 + b16) * 256 + nb + quad * 4] = res;
    }
  }
}

// Shared LSTM, batch-parallel, ZERO exchange: 16 WGs x 1024 thr, one per batch.
// W_hh f16: K=0..191 in 96 VGPRs/thread, K=192..255 in 128 KB LDS.
// Round-16 delta: amdgpu_waves_per_eu(4,4) pins occupancy so the allocator
// uses the full 128-VGPR budget (round-15 had VGPR_Count=64 -> wr spilled to
// scratch, ~2.5 us/step of scratch traffic).
__global__ __launch_bounds__(1024)
__attribute__((amdgpu_waves_per_eu(4, 4)))
void lstm_b2(const float* __restrict__ x1,
             const float* __restrict__ W_hh,
             float* __restrict__ hsB){
  extern __shared__ char smem[];
  uint4* wl4 = (uint4*)smem;                    // [8][1024] uint4 (K=192..255)
  uint4* hT4 = (uint4*)(smem + 131072);         // [32] uint4: h as f16 pairs
  float* pre = (float*)(smem + 131584);         // [1024]

  const int tid = threadIdx.x;
  const int bb = blockIdx.x;
  const float* wrow = &W_hh[tid * 256];

  // ---- one-time: W row -> 96 VGPRs (K=0..191) + LDS (K=192..255) ----
  unsigned wr[96];
  #pragma unroll
  for (int m = 0; m < 96; ++m)
    wr[m] = packh2(wrow[2 * m], wrow[2 * m + 1]);
  #pragma unroll
  for (int i = 0; i < 8; ++i) {
    const float* wp = &wrow[192 + 8 * i];
    uint4 v;
    v.x = packh2(wp[0], wp[1]); v.y = packh2(wp[2], wp[3]);
    v.z = packh2(wp[4], wp[5]); v.w = packh2(wp[6], wp[7]);
    wl4[i * 1024 + tid] = v;
  }
  if (tid < 32) hT4[tid] = make_uint4(0u, 0u, 0u, 0u);
  float cst = 0.f;                 // c-state (tid<256)
  float xcur = x1[(0 * 16 + bb) * 1024 + tid];
  __syncthreads();

  for (int t = 0; t < T_LEN; ++t) {
    // prefetch next step's x1 (independent of everything this step)
    float xnext = (t + 1 < T_LEN) ? x1[((t + 1) * 16 + bb) * 1024 + tid] : 0.f;
    // 4 independent accumulator chains; x added at the end (latency hidden)
    float a0 = 0.f, a1 = 0.f, a2 = 0.f, a3 = 0.f;
    // VGPR W part: K=0..191 (24 uint4 groups, round-robin over chains)
    #pragma unroll
    for (int i = 0; i < 24; i += 4) {
      uint4 h0 = hT4[i], h1 = hT4[i + 1], h2 = hT4[i + 2], h3 = hT4[i + 3];
      a0 = fdot2(wr[4 * i],      h0.x, a0); a0 = fdot2(wr[4 * i + 1],  h0.y, a0);
      a0 = fdot2(wr[4 * i + 2],  h0.z, a0); a0 = fdot2(wr[4 * i + 3],  h0.w, a0);
      a1 = fdot2(wr[4 * i + 4],  h1.x, a1); a1 = fdot2(wr[4 * i + 5],  h1.y, a1);
      a1 = fdot2(wr[4 * i + 6],  h1.z, a1); a1 = fdot2(wr[4 * i + 7],  h1.w, a1);
      a2 = fdot2(wr[4 * i + 8],  h2.x, a2); a2 = fdot2(wr[4 * i + 9],  h2.y, a2);
      a2 = fdot2(wr[4 * i + 10], h2.z, a2); a2 = fdot2(wr[4 * i + 11], h2.w, a2);
      a3 = fdot2(wr[4 * i + 12], h3.x, a3); a3 = fdot2(wr[4 * i + 13], h3.y, a3);
      a3 = fdot2(wr[4 * i + 14], h3.z, a3); a3 = fdot2(wr[4 * i + 15], h3.w, a3);
    }
    // LDS W part: K=192..255 (8 uint4 groups, 2 per chain)
    #pragma unroll
    for (int i = 0; i < 8; i += 4) {
      uint4 w0 = wl4[(i)     * 1024 + tid];
      uint4 w1 = wl4[(i + 1) * 1024 + tid];
      uint4 w2 = wl4[(i + 2) * 1024 + tid];
      uint4 w3 = wl4[(i + 3) * 1024 + tid];
      uint4 h0 = hT4[24 + i], h1 = hT4[25 + i], h2 = hT4[26 + i], h3 = hT4[27 + i];
      a0 = fdot2(w0.x, h0.x, a0); a0 = fdot2(w0.y, h0.y, a0);
      a0 = fdot2(w0.z, h0.z, a0); a0 = fdot2(w0.w, h0.w, a0);
      a1 = fdot2(w1.x, h1.x, a1); a1 = fdot2(w1.y, h1.y, a1);
      a1 = fdot2(w1.z, h1.z, a1); a1 = fdot2(w1.w, h1.w, a1);
      a2 = fdot2(w2.x, h2.x, a2); a2 = fdot2(w2.y, h2.y, a2);
      a2 = fdot2(w2.z, h2.z, a2); a2 = fdot2(w2.w, h2.w, a2);
      a3 = fdot2(w3.x, h3.x, a3); a3 = fdot2(w3.y, h3.y, a3);
      a3 = fdot2(w3.z, h3.z, a3); a3 = fdot2(w3.w, h3.w, a3);
    }
    pre[tid] = ((a0 + a1) + (a2 + a3)) + xcur;
    __syncthreads();
    if (tid < 256) {
      float pi = pre[tid], pf = pre[tid + 256], pg = pre[tid + 512], po = pre[tid + 768];
      float cn = fmaf(sigm(pf), cst, sigm(pi) * tanh_f(pg));
      float hh = sigm(po) * tanh_f(cn);
      cst = cn;
      hsB[(bb * 192 + t) * 256 + tid] = hh;
      float hp_ = __shfl_xor(hh, 1);
      if ((tid & 1) == 0) ((unsigned*)hT4)[tid >> 1] = packh2(hh, hp_);
    }
    __syncthreads();
    xcur = xnext;
  }
}

// Task loop: 128 WGs x 1024 thr; bb = bid&15, s = bid>>4 owns c in [32s,32s+32).
// Round-10 proven version (2 RTT/step, sp-major mailboxes, s_sleep backoff).
__global__ __launch_bounds__(1024) void task_kernel(
    const float* __restrict__ xb3, const float* __restrict__ xpre,
    const float* __restrict__ hsB, const float* __restrict__ Us_w,
    const float* __restrict__ Us_b, const float* __restrict__ Wc,
    const float* __restrict__ Ws_w,
    u64* __restrict__ Pbuf, u64* __restrict__ Hbuf, u64* __restrict__ HPbuf,
    float* __restrict__ out){
  extern __shared__ char smem[];
  // prologue views
  unsigned* hsL  = (unsigned*)smem;               // [192][129] u32
  unsigned* Ws1L = (unsigned*)(smem + 99072);     // [32][129]
  float*    baseS= (float*)(smem + 115584);       // [192][33]
  // main views
  unsigned* WcH  = (unsigned*)smem;               // 16384 u32: Wc h-part
  unsigned* Ws2P = (unsigned*)(smem + 65536);     // [256 c][17] u32: Ws2 own-K slice
  float* prel    = (float*)(smem + 82944);        // [128][13]
  float* eel     = (float*)(smem + 89600);        // 192
  unsigned* h2l  = (unsigned*)(smem + 90368);     // 128 (full h pairs)
  unsigned* h2own= (unsigned*)(smem + 90880);     // 16 (own h slice pairs)
  float* hterml  = (float*)(smem + 90944);        // 32
  float* usl     = (float*)(smem + 91072);        // 32
  float* msc     = (float*)(smem + 91200);        // 1
  unsigned* G2   = (unsigned*)(smem + 99072);     // [128][97] u32

  const int tid = threadIdx.x;
  const int bb = blockIdx.x & 15;
  const int s  = blockIdx.x >> 4;

  // ---- P1: stage hs (f16) + Ws1 slice ----
  for (int idx = tid; idx < 24576; idx += 1024) {
    int tp = idx >> 7, k2 = idx & 127;
    const float* hp = &hsB[(bb * 192 + tp) * 256 + 2 * k2];
    hsL[tp * 129 + k2] = packh2(hp[0], hp[1]);
  }
  for (int idx = tid; idx < 4096; idx += 1024) {
    int c = idx >> 7, k2 = idx & 127;
    const float* wp = &Ws_w[(32 * s + c) * 768 + 2 * k2];
    Ws1L[c * 129 + k2] = packh2(wp[0], wp[1]);
  }
  __syncthreads();
  // ---- P2: base_s = xb3 + hs @ Ws1^T ----
  {
    int c = tid & 31, g = tid >> 5;
    float a6[6];
    #pragma unroll
    for (int j = 0; j < 6; ++j)
      a6[j] = xb3[((g * 6 + j) * 16 + bb) * 256 + 32 * s + c];
    for (int k2 = 0; k2 < 128; ++k2) {
      unsigned wv = Ws1L[c * 129 + k2];
      #pragma unroll
      for (int j = 0; j < 6; ++j)
        a6[j] = fdot2(wv, hsL[(g * 6 + j) * 129 + k2], a6[j]);
    }
    #pragma unroll
    for (int j = 0; j < 6; ++j)
      baseS[(g * 6 + j) * 33 + c] = a6[j];
  }
  __syncthreads();
  // ---- P3a: persistent base registers ----
  unsigned bs4[4] = {0u, 0u, 0u, 0u};
  if (tid < 768) {
    int tp = tid >> 2, q = tid & 3;
    #pragma unroll
    for (int j2 = 0; j2 < 4; ++j2)
      bs4[j2] = packh2(baseS[tp * 33 + q * 8 + 2 * j2],
                       baseS[tp * 33 + q * 8 + 2 * j2 + 1]);
  }
  __syncthreads();
  // ---- P3b: G2[l][j] = f16 pairs over t of (Wc_R[l,:] @ hs[t,:]) ----
  {
    int l = tid & 127, tg = tid >> 7;
    int row = (l >> 5) * 256 + 32 * s + (l & 31);
    const float* wr = &Wc[row * 768 + 256];
    float acc[24];
    #pragma unroll
    for (int i = 0; i < 24; ++i) acc[i] = 0.f;
    for (int kc = 0; kc < 128; kc += 16) {
      unsigned wv[16];
      #pragma unroll
      for (int i = 0; i < 16; ++i) {
        float2 wp2 = *(const float2*)&wr[2 * (kc + i)];
        wv[i] = packh2(wp2.x, wp2.y);
      }
      #pragma unroll
      for (int tt = 0; tt < 24; ++tt) {
        const unsigned* hp = &hsL[(tg * 24 + tt) * 129 + kc];
        float a = acc[tt];
        #pragma unroll
        for (int i = 0; i < 16; ++i) a = fdot2(wv[i], hp[i], a);
        acc[tt] = a;
      }
    }
    #pragma unroll
    for (int i = 0; i < 12; ++i)
      G2[l * 97 + tg * 12 + i] = packh2(acc[2 * i], acc[2 * i + 1]);
  }
  __syncthreads();
  // ---- P4: main weight fills ----
  for (int idx = tid; idx < 16384; idx += 1024) {
    int j = idx & 3, l = (idx >> 2) & 127, k2q = idx >> 9;
    int k2 = k2q * 4 + j;
    int row = (l >> 5) * 256 + 32 * s + (l & 31);
    const float* wp = &Wc[row * 768 + 512 + 2 * k2];   // h-part cols
    WcH[idx] = packh2(wp[0], wp[1]);
  }
  for (int idx = tid; idx < 4096; idx += 1024) {
    int c = idx >> 4, j = idx & 15;                    // Ws2[:, own h K-slice]
    const float* wp = &Ws_w[c * 768 + 256 + 2 * (16 * s + j)];
    Ws2P[c * 17 + j] = packh2(wp[0], wp[1]);
  }
  if (tid < 32) usl[tid] = Us_w[32 * s + tid];
  const float usb = Us_b[0];
  __syncthreads();

  u64* Pb  = Pbuf + (bb * 8) * 192;        // [8 sp][192 tp]
  u64* Hb  = Hbuf + bb * 256;
  u64* HPb = HPbuf + (bb * 8) * 256;       // [8 sp][256 c]
  const uint4* wp4 = (const uint4*)WcH;
  const uint4* av4 = (const uint4*)h2l;
  float creg = 0.f;       // c-state (tid<32)

  for (int t = 0; t < T_LEN; ++t) {
    const unsigned seq = (unsigned)(t + 1);
    float xp0 = 0.f, xp1 = 0.f, xp2 = 0.f, xp3 = 0.f;
    if (tid < 32) {
      const float* xq = &xpre[(t * 16 + bb) * 1024 + 32 * s + tid];
      xp0 = xq[0]; xp1 = xq[256]; xp2 = xq[512]; xp3 = xq[768];
    }
    // S1: poll h (full) + hterm partials (own 32 c), one RTT
    if (t > 0) {
      if (tid < 256) {
        int c = tid >> 3, sp = tid & 7;       // all 8 sp for c within one wave
        u64 v = gld64(&HPb[sp * 256 + 32 * s + c]);
        while ((unsigned)v != (unsigned)t) {
          __builtin_amdgcn_s_sleep(1);
          v = gld64(&HPb[sp * 256 + 32 * s + c]);
        }
        float a = __uint_as_float((unsigned)(v >> 32));
        a += __shfl_xor(a, 1); a += __shfl_xor(a, 2); a += __shfl_xor(a, 4);
        if (sp == 0) hterml[c] = a;
      } else if (tid < 512) {
        int col = tid - 256;
        u64 v = gld64(&Hb[col]);
        while ((unsigned)v != (unsigned)t) {
          __builtin_amdgcn_s_sleep(1);
          v = gld64(&Hb[col]);
        }
        float hvv = __uint_as_float((unsigned)(v >> 32));
        float hp_ = __shfl_xor(hvv, 1);
        if ((col & 1) == 0) h2l[col >> 1] = packh2(hvv, hp_);
      }
    } else {
      if (tid < 32) hterml[tid] = 0.f;
      if (tid < 128) h2l[tid] = 0u;
    }
    __syncthreads();                 // B1
    // S5: score partials over own 32 c for all 192 tp; publish p_s
    if (tid < 768) {
      int tp = tid >> 2, q = tid & 3;
      float p = 0.f;
      #pragma unroll
      for (int m = 0; m < 4; ++m) {
        float2 bv = unp2(bs4[m]);
        int c0 = q * 8 + 2 * m;
        p += usl[c0]     * tanh_f(bv.x + hterml[c0]);
        p += usl[c0 + 1] * tanh_f(bv.y + hterml[c0 + 1]);
      }
      p += __shfl_xor(p, 1);
      p += __shfl_xor(p, 2);
      if ((tid & 3) == 0)
        gst64(&Pb[s * 192 + tp], ((u64)__float_as_uint(p) << 32) | seq);
    }
    // hgate GEMV (p-RTT shadow): pre_h[l] partials, 8-way K-split
    {
      int l = tid & 127, kq = tid >> 7;
      float a = 0.f;
      #pragma unroll
      for (int i = 0; i < 4; ++i) {
        uint4 w4 = wp4[(kq * 4 + i) * 128 + l];
        uint4 a4 = av4[kq * 4 + i];
        a = fdot2(w4.x, a4.x, a); a = fdot2(w4.y, a4.y, a);
        a = fdot2(w4.z, a4.z, a); a = fdot2(w4.w, a4.w, a);
      }
      prel[l * 13 + kq] = a;
    }
    // S6: p poll + exp (bounded scores, no max-sub)
    if (tid < 192) {
      u64 v[8];
      for (;;) {
        bool ok = true;
        #pragma unroll
        for (int sp = 0; sp < 8; ++sp) {
          v[sp] = gld64(&Pb[sp * 192 + tid]);
          ok &= ((unsigned)v[sp] == seq);
        }
        if (ok) break;
        __builtin_amdgcn_s_sleep(1);
      }
      float sum = 0.f;
      #pragma unroll
      for (int sp = 0; sp < 8; ++sp) sum += __uint_as_float((unsigned)(v[sp] >> 32));
      eel[tid] = __expf(sum + usb);
    }
    __syncthreads();                 // B5
    // msc reduce (wave0) + G-part (tid>=512)
    if (tid < 64) {
      float aa = eel[tid] + eel[tid + 64] + eel[tid + 128];
      #pragma unroll
      for (int off = 32; off >= 1; off >>= 1) aa += __shfl_xor(aa, off);
      if (tid == 0) msc[0] = 1.f / aa;
    }
    if (tid >= 512) {
      int l = (tid - 512) & 127, tq = (tid - 512) >> 7;
      const unsigned* gp = &G2[l * 97 + tq * 24];
      const float2* ep = (const float2*)&eel[tq * 48];
      float a = 0.f;
      #pragma unroll
      for (int i = 0; i < 24; ++i) {
        float2 g = unp2(gp[i]);
        float2 e = ep[i];
        a = fmaf(g.x, e.x, a); a = fmaf(g.y, e.y, a);
      }
      prel[l * 13 + 8 + tq] = a;
    }
    __syncthreads();                 // B9
    // epilogue: gates for own 32 h-cols; publish h early
    if (tid < 32) {
      float m = msc[0];
      float pr[4];
      #pragma unroll
      for (int g = 0; g < 4; ++g) {
        const float* pp = &prel[(g * 32 + tid) * 13];
        float hsum = pp[0] + pp[1] + pp[2] + pp[3] + pp[4] + pp[5] + pp[6] + pp[7];
        float gsum = pp[8] + pp[9] + pp[10] + pp[11];
        pr[g] = hsum + m * gsum;
      }
      pr[0] += xp0; pr[1] += xp1; pr[2] += xp2; pr[3] += xp3;
      float cn = fmaf(sigm(pr[1]), creg, sigm(pr[0]) * tanh_f(pr[2]));
      float hh = sigm(pr[3]) * tanh_f(cn);
      creg = cn;
      gst64(&Hb[32 * s + tid], ((u64)__float_as_uint(hh) << 32) | seq);
      out[(bb * 192 + t) * 256 + 32 * s + tid] = hh;
      float hp_ = __shfl_xor(hh, 1);
      if ((tid & 1) == 0) h2own[tid >> 1] = packh2(hh, hp_);
    }
    __syncthreads();                 // B10
    // producer-side hterm partials: hpart[c] = Ws2[c, own K] @ h_own; publish
    if (tid < 256) {
      float a = 0.f;
      const unsigned* wp = &Ws2P[tid * 17];
      #pragma unroll
      for (int j = 0; j < 16; ++j) a = fdot2(wp[j], h2own[j], a);
      gst64(&HPb[s * 256 + tid], ((u64)__float_as_uint(a) << 32) | seq);
    }
  }
}

extern "C" void kernel_launch(void* const* d_in, const int* in_sizes, int n_in,
                              void* d_out, int out_size, void* d_ws, size_t ws_size,
                              hipStream_t stream) {
  (void)in_sizes; (void)n_in; (void)out_size; (void)ws_size;
  const float* x    = (const float*)d_in[0];
  const float* W_ih = (const float*)d_in[1];
  const float* W_hh = (const float*)d_in[2];
  const float* b_l  = (const float*)d_in[3];
  const float* Ws_w = (const float*)d_in[4];
  const float* Ws_b = (const float*)d_in[5];
  const float* Us_w = (const float*)d_in[6];
  const float* Us_b = (const float*)d_in[7];
  const float* Wc   = (const float*)d_in[8];
  const float* bc   = (const float*)d_in[9];
  float* out = (float*)d_out;
  float* ws = (float*)d_ws;

  (void)hipFuncSetAttribute((const void*)task_kernel,
                            hipFuncAttributeMaxDynamicSharedMemorySize, 160 * 1024);
  (void)hipFuncSetAttribute((const void*)lstm_b2,
                            hipFuncAttributeMaxDynamicSharedMemorySize, 160 * 1024);

  // zero exchange region (P, H, HP — seq tags restart at 1 each launch)
  initk<<<64, 256, 0, stream>>>(ws + OFF_P, EXCH_WORDS);

  // fused MFMA x-projections: x1 (plain), xpre, xb3
  proj3m<<<dim3(36, 96), 256, 0, stream>>>(x, W_ih, b_l, Wc, bc, Ws_w, Ws_b, ws);

  // shared LSTM: batch-parallel, zero-exchange, W_hh in VGPR(96)+LDS(128KB)
  lstm_b2<<<16, 1024, SMEM_LSTM, stream>>>(ws + OFF_X1F, W_hh, ws + OFF_HSB);

  // task loop
  task_kernel<<<128, 1024, SMEM_TASK, stream>>>(
      ws + OFF_XB3, ws + OFF_XPRE, ws + OFF_HSB, Us_w, Us_b, Wc, Ws_w,
      (u64*)(ws + OFF_P), (u64*)(ws + OFF_H), (u64*)(ws + OFF_HP), out);
}